// Round 12
// baseline (486.269 us; speedup 1.0000x reference)
//
#include <hip/hip_runtime.h>

__device__ __forceinline__ float silu_f(float x) { return x / (1.f + __expf(-x)); }

__device__ __forceinline__ void atomicMaxF(float* addr, float val) {
    if (val >= 0.f) atomicMax((int*)addr, __float_as_int(val));
    else            atomicMin((unsigned int*)addr, __float_as_uint(val));
}

// f32 -> bf16 (RNE) and back
__device__ __forceinline__ unsigned short f2bf(float x) {
    unsigned int u = __float_as_uint(x);
    return (unsigned short)((u + 0x7fffu + ((u >> 16) & 1u)) >> 16);
}
__device__ __forceinline__ float bf2f(unsigned short h) {
    return __uint_as_float(((unsigned int)h) << 16);
}
__device__ __forceinline__ float bf_lo(unsigned int u) { return __uint_as_float(u << 16); }
__device__ __forceinline__ float bf_hi(unsigned int u) { return __uint_as_float(u & 0xffff0000u); }
__device__ __forceinline__ float bfdot(unsigned int a, unsigned int b) {
    return bf_lo(a) * bf_lo(b) + bf_hi(a) * bf_hi(b);
}

__global__ void fill_i(int* __restrict__ p, int v, int n) {
    int i = blockIdx.x * blockDim.x + threadIdx.x;
    if (i < n) p[i] = v;
}

// combined histogram over [L | P | X] target-node space
__global__ __launch_bounds__(256) void hist_all_kernel(const int* __restrict__ tgtL,
        const int* __restrict__ tgtP, const int* __restrict__ ctgt, int* __restrict__ count,
        int E_L, int E_P, int E_X, int N_L, int N_P) {
    int e = blockIdx.x * blockDim.x + threadIdx.x;
    if (e < E_L) atomicAdd(&count[tgtL[e]], 1);
    else if (e < E_L + E_P) atomicAdd(&count[N_L + tgtP[e - E_L]], 1);
    else if (e < E_L + E_P + E_X) atomicAdd(&count[N_L + N_P + ctgt[e - E_L - E_P]], 1);
}

// ---- hierarchical scan ----
__global__ __launch_bounds__(256) void scan_blocksum_kernel(const int* __restrict__ count,
                                                            int* __restrict__ bsum, int n) {
    int b = blockIdx.x, t = threadIdx.x;
    int base = b * 4096 + t * 16;
    int s = 0;
#pragma unroll
    for (int k = 0; k < 16; ++k) {
        int idx = base + k;
        s += (idx < n) ? count[idx] : 0;
    }
#pragma unroll
    for (int off = 1; off < 64; off <<= 1) s += __shfl_xor(s, off, 64);
    __shared__ int ws[4];
    int lane = t & 63, wid = t >> 6;
    if (lane == 0) ws[wid] = s;
    __syncthreads();
    if (t == 0) bsum[b] = ws[0] + ws[1] + ws[2] + ws[3];
}

__global__ void scan_top_kernel(int* __restrict__ bsum, int nb, float* __restrict__ csc) {
    if (threadIdx.x == 0) {
        int run = 0;
        for (int i = 0; i < nb; ++i) { int c = bsum[i]; bsum[i] = run; run += c; }
        csc[0] = -3.4e38f; csc[1] = 0.f;
    }
}

__global__ __launch_bounds__(256) void scan_apply_kernel(const int* __restrict__ count,
        const int* __restrict__ bsum, int* __restrict__ rowptr, int* __restrict__ cursor,
        int n, int E) {
    int b = blockIdx.x, t = threadIdx.x;
    int base = b * 4096 + t * 16;
    int v[16];
    int s = 0;
#pragma unroll
    for (int k = 0; k < 16; ++k) {
        int idx = base + k;
        v[k] = (idx < n) ? count[idx] : 0;
        s += v[k];
    }
    int lane = t & 63, wid = t >> 6;
    int inc = s;
#pragma unroll
    for (int off = 1; off < 64; off <<= 1) {
        int o = __shfl_up(inc, off, 64);
        if (lane >= off) inc += o;
    }
    __shared__ int ws[4];
    if (lane == 63) ws[wid] = inc;
    __syncthreads();
    int woff = 0;
    for (int w = 0; w < wid; ++w) woff += ws[w];
    int prefix = bsum[b] + woff + (inc - s);
#pragma unroll
    for (int k = 0; k < 16; ++k) {
        int idx = base + k;
        if (idx < n) { rowptr[idx] = prefix; cursor[idx] = prefix; prefix += v[k]; }
    }
    if (b == 0 && t == 0) rowptr[n] = E;
}

// combined CSR fill, 4-byte packed payloads
__global__ __launch_bounds__(256) void pre_all_kernel(const int* __restrict__ eL,
        const int* __restrict__ eP, const int* __restrict__ csrc, const int* __restrict__ ctgt,
        const float* __restrict__ posL, const float* __restrict__ posP,
        int* __restrict__ cursor, unsigned int* __restrict__ sdp,
        int E_L, int E_P, int E_X, int N_L, int N_P) {
    int e = blockIdx.x * blockDim.x + threadIdx.x;
    if (e >= E_L + E_P + E_X) return;
    unsigned int pack;
    int node;
    if (e < E_L + E_P) {
        const int* ed; const float* pos; int idx, E, nbase;
        if (e < E_L) { ed = eL; pos = posL; idx = e; E = E_L; nbase = 0; }
        else         { ed = eP; pos = posP; idx = e - E_L; E = E_P; nbase = N_L; }
        int si = ed[idx], ti = ed[E + idx];
        node = nbase + ti;
        float dx = pos[si * 3 + 0] - pos[ti * 3 + 0];
        float dy = pos[si * 3 + 1] - pos[ti * 3 + 1];
        float dz = pos[si * 3 + 2] - pos[ti * 3 + 2];
        float dist = sqrtf(dx * dx + dy * dy + dz * dz);
        int dq = min((int)(dist * 4096.f), 65535);
        pack = (unsigned int)(si + nbase) | ((unsigned int)dq << 16);
    } else {
        int idx = e - E_L - E_P;
        int ti = ctgt[idx];
        pack = (unsigned int)csrc[idx] | ((unsigned int)ti << 16);
        node = N_L + N_P + ti;
    }
    int p = atomicAdd(&cursor[node], 1);
    sdp[p] = pack;
}

// packed RBF@We table
__global__ __launch_bounds__(96) void rbf_table_pack_kernel(const float* __restrict__ We_L,
        const float* __restrict__ We_P, unsigned int* __restrict__ T2_L,
        unsigned int* __restrict__ T2_P) {
    int b = blockIdx.x;
    const float* We = (b < 1024) ? We_L : We_P;
    unsigned int* T2 = (b < 1024) ? T2_L : T2_P;
    int i = (b < 1024) ? b : b - 1024;
    int h = threadIdx.x;
    float d0 = (float)i * 0.015625f, d1 = (float)(i + 1) * 0.015625f;
    float a0 = 0.f, a1 = 0.f;
#pragma unroll
    for (int g = 0; g < 16; ++g) {
        float w = We[g * 96 + h];
        float t0 = d0 - 0.66666667f * (float)g;
        float t1 = d1 - 0.66666667f * (float)g;
        a0 += __expf(-1.125f * t0 * t0) * w;
        a1 += __expf(-1.125f * t1 * t1) * w;
    }
    T2[i * 96 + h] = (unsigned int)f2bf(a0) | ((unsigned int)f2bf(a1 - a0) << 16);
}

// Combined L+P GATv2: half-wave per node; lane owns h in {2l, 2l+1, 64+l} (paired loads).
__global__ __launch_bounds__(256) void gat_all_kernel(const int* __restrict__ rowptr,
        const unsigned int* __restrict__ sdp, const unsigned short* __restrict__ xlb,
        const unsigned short* __restrict__ xrb,
        const unsigned int* __restrict__ T2_L, const unsigned int* __restrict__ T2_P,
        const float* __restrict__ att_L, const float* __restrict__ att_P,
        const float* __restrict__ bias_L, const float* __restrict__ bias_P,
        float* __restrict__ s_L, float* __restrict__ s_P, int N_L, int Ncomb) {
    int tid = threadIdx.x;
    int l = tid & 31;
    int n = blockIdx.x * 8 + (tid >> 5);
    if (n >= Ncomb) return;
    bool isL = n < N_L;
    const unsigned int* T2 = isL ? T2_L : T2_P;
    const float* att = isL ? att_L : att_P;
    const float* bias = isL ? bias_L : bias_P;
    float* srow = isL ? (s_L + (size_t)n * 96) : (s_P + (size_t)(n - N_L) * 96);
    int h01 = 2 * l, h2 = 64 + l;
    float att0 = att[h01], att1 = att[h01 + 1], att2 = att[h2];
    size_t nb = (size_t)n * 96;
    unsigned int xru = *(const unsigned int*)&xrb[nb + h01];
    float xr0 = bf_lo(xru), xr1 = bf_lo(xru >> 16), xr2 = bf2f(xrb[nb + h2]);
    int beg = rowptr[n], end = rowptr[n + 1];
    float m = -3.4e38f, d = 0.f, a0 = 0.f, a1 = 0.f, a2 = 0.f;
    for (int j = beg; j < end; j += 4) {
        uint2 tpA[4]; unsigned int tp2[4];
        unsigned int xA[4]; unsigned short x2[4];
        float ff[4];
#pragma unroll
        for (int k = 0; k < 4; ++k) {
            int jj = min(j + k, end - 1);
            unsigned int u = sdp[jj];
            int src = (int)(u & 0xffffu);
            int dq = (int)(u >> 16);
            int i = dq >> 6;
            ff[k] = (float)(dq & 63) * 0.015625f;
            const unsigned int* tr = T2 + (size_t)i * 96;
            tpA[k] = *(const uint2*)&tr[h01];
            tp2[k] = tr[h2];
            const unsigned short* xp = xlb + (size_t)src * 96;
            xA[k] = *(const unsigned int*)&xp[h01];
            x2[k] = xp[h2];
        }
        float y0[4], y1[4], y2[4], lt[4];
#pragma unroll
        for (int k = 0; k < 4; ++k) {
            y0[k] = bf_lo(xA[k]); y1[k] = bf_lo(xA[k] >> 16); y2[k] = bf2f(x2[k]);
            float v0 = y0[k] + xr0 + bf_lo(tpA[k].x) + ff[k] * bf_hi(tpA[k].x);
            float v1 = y1[k] + xr1 + bf_lo(tpA[k].y) + ff[k] * bf_hi(tpA[k].y);
            float v2 = y2[k] + xr2 + bf_lo(tp2[k]) + ff[k] * bf_hi(tp2[k]);
            v0 = fmaxf(v0, 0.f) + 0.2f * fminf(v0, 0.f);
            v1 = fmaxf(v1, 0.f) + 0.2f * fminf(v1, 0.f);
            v2 = fmaxf(v2, 0.f) + 0.2f * fminf(v2, 0.f);
            float t = v0 * att0 + v1 * att1 + v2 * att2;
#pragma unroll
            for (int off = 1; off < 32; off <<= 1) t += __shfl_xor(t, off, 64);
            lt[k] = (j + k < end) ? t : -3.4e38f;
        }
        float bm = fmaxf(fmaxf(lt[0], lt[1]), fmaxf(lt[2], lt[3]));
        float nm = fmaxf(m, bm);
        float sc = __expf(m - nm);
        d *= sc; a0 *= sc; a1 *= sc; a2 *= sc;
#pragma unroll
        for (int k = 0; k < 4; ++k) {
            float w = __expf(lt[k] - nm);
            d += w;
            a0 += w * y0[k]; a1 += w * y1[k]; a2 += w * y2[k];
        }
        m = nm;
    }
    float inv = (d > 0.f) ? 1.f / d : 0.f;
    srow[h01]     += silu_f(a0 * inv + bias[h01]);
    srow[h01 + 1] += silu_f(a1 * inv + bias[h01 + 1]);
    srow[h2]      += silu_f(a2 * inv + bias[h2]);
}

// edge-parallel cross logits
__global__ __launch_bounds__(256) void cross_logit_e_kernel(const unsigned int* __restrict__ sdX,
        const unsigned short* __restrict__ qnb, const unsigned short* __restrict__ knb,
        float* __restrict__ clog_s, float* __restrict__ csc, int E) {
    int e = blockIdx.x * blockDim.x + threadIdx.x;
    float logit = -3.4e38f;
    if (e < E) {
        unsigned int u = sdX[e];
        int src = (int)(u & 0xffffu);
        int tgt = (int)(u >> 16);
        const uint4* q4 = (const uint4*)(qnb + (size_t)tgt * 96);
        const uint4* k4 = (const uint4*)(knb + (size_t)src * 96);
        float acc = 0.f;
#pragma unroll
        for (int i = 0; i < 12; ++i) {
            uint4 qa = q4[i], ka = k4[i];
            acc += bfdot(qa.x, ka.x) + bfdot(qa.y, ka.y) + bfdot(qa.z, ka.z) + bfdot(qa.w, ka.w);
        }
        logit = acc * 0.125f;
        clog_s[e] = logit;
    }
    __shared__ float red[256];
    red[threadIdx.x] = logit; __syncthreads();
    for (int s = 128; s > 0; s >>= 1) {
        if (threadIdx.x < s) red[threadIdx.x] = fmaxf(red[threadIdx.x], red[threadIdx.x + s]);
        __syncthreads();
    }
    if (threadIdx.x == 0) atomicMaxF(&csc[0], red[0]);
}

__global__ __launch_bounds__(256) void cross_denom_kernel(const float* __restrict__ clog_s,
                                                          float* __restrict__ csc, int E) {
    int e = blockIdx.x * blockDim.x + threadIdx.x;
    float a = 0.f;
    float mg = csc[0];
    if (e < E) a = __expf(clog_s[e] - mg);
    __shared__ float red[256];
    red[threadIdx.x] = a; __syncthreads();
    for (int s = 128; s > 0; s >>= 1) {
        if (threadIdx.x < s) red[threadIdx.x] += red[threadIdx.x + s];
        __syncthreads();
    }
    if (threadIdx.x == 0) atomicAdd(&csc[1], red[0]);
}

// cross apply: half-wave per L node, paired loads
__global__ __launch_bounds__(256) void cross_apply_v4_kernel(const int* __restrict__ rowptr,
        const unsigned int* __restrict__ sdp, const float* __restrict__ clog_s,
        const unsigned short* __restrict__ vnb, const float* __restrict__ csc,
        float* __restrict__ sL, int N, int baseX) {
    int tid = threadIdx.x;
    int l = tid & 31;
    int n = blockIdx.x * 8 + (tid >> 5);
    if (n >= N) return;
    int beg = rowptr[n], end = rowptr[n + 1];
    if (beg == end) return;
    int h01 = 2 * l, h2 = 64 + l;
    float M = csc[0], invD = 1.f / csc[1];
    float a0 = 0.f, a1 = 0.f, a2 = 0.f;
    for (int j = beg; j < end; j += 4) {
        unsigned int vA[4]; unsigned short v2[4]; float w[4];
#pragma unroll
        for (int k = 0; k < 4; ++k) {
            int jj = min(j + k, end - 1);
            int src = (int)(sdp[jj] & 0xffffu);
            const unsigned short* vp = vnb + (size_t)src * 96;
            vA[k] = *(const unsigned int*)&vp[h01];
            v2[k] = vp[h2];
            w[k] = (j + k < end) ? __expf(clog_s[jj - baseX] - M) : 0.f;
        }
#pragma unroll
        for (int k = 0; k < 4; ++k) {
            a0 += w[k] * bf_lo(vA[k]); a1 += w[k] * bf_lo(vA[k] >> 16); a2 += w[k] * bf2f(v2[k]);
        }
    }
    size_t nb = (size_t)n * 96;
    sL[nb + h01]     += a0 * invD;
    sL[nb + h01 + 1] += a1 * invD;
    sL[nb + h2]      += a2 * invD;
}

// ---------- vectorized dense kernels ----------

// fused embed + dual GAT-linear; 16 rows/block, two LDS buffers (xs + padded ss).
// thread: 4 h-cols (hg=t%24) x 2 rows (rg=t/24, 8 groups).
__global__ __launch_bounds__(192) void enc_all_kernel(
        const float* __restrict__ x_L, const float* __restrict__ x_P,
        const float* __restrict__ WembL, const float* __restrict__ bembL,
        const float* __restrict__ WembP, const float* __restrict__ bembP,
        const float* __restrict__ WlL, const float* __restrict__ blL,
        const float* __restrict__ WrL, const float* __restrict__ brL,
        const float* __restrict__ WlP, const float* __restrict__ blP,
        const float* __restrict__ WrP, const float* __restrict__ brP,
        float* __restrict__ s_L, float* __restrict__ s_P,
        unsigned short* __restrict__ xlb, unsigned short* __restrict__ xrb,
        int N_L, int N_P, int D_L, int D_P, int BL) {
    __shared__ float xs[16 * 167];
    __shared__ float ss[16 * 100];
    int b = blockIdx.x;
    bool isL = b < BL;
    const float* x    = isL ? x_L : x_P;
    const float* Wemb = isL ? WembL : WembP;
    const float* bemb = isL ? bembL : bembP;
    const float* Wl   = isL ? WlL : WlP;
    const float* bl   = isL ? blL : blP;
    const float* Wr   = isL ? WrL : WrP;
    const float* br   = isL ? brL : brP;
    float* sOut = isL ? s_L : s_P;
    int N = isL ? N_L : N_P;
    int D = isL ? D_L : D_P;
    int n0 = (isL ? b : b - BL) * 16;
    int cbase = isL ? 0 : N_L;
    int t = threadIdx.x;
    int hg = t % 24, h4 = hg * 4;
    int rg = t / 24;  // 0..7, rows rg*2, rg*2+1
    for (int i = t; i < 16 * D; i += 192) {
        int r = i / D, dd = i - r * D, nn = n0 + r;
        xs[i] = (nn < N) ? x[(size_t)nn * D + dd] : 0.f;
    }
    __syncthreads();
    float4 be = *(const float4*)&bemb[h4];
    float acc[2][4];
#pragma unroll
    for (int r = 0; r < 2; ++r) { acc[r][0] = be.x; acc[r][1] = be.y; acc[r][2] = be.z; acc[r][3] = be.w; }
    const float* xrow = &xs[rg * 2 * D];
    for (int dd = 0; dd < D; ++dd) {
        float4 w = *(const float4*)&Wemb[dd * 96 + h4];
#pragma unroll
        for (int r = 0; r < 2; ++r) {
            float xv = xrow[r * D + dd];
            acc[r][0] += xv * w.x; acc[r][1] += xv * w.y;
            acc[r][2] += xv * w.z; acc[r][3] += xv * w.w;
        }
    }
#pragma unroll
    for (int r = 0; r < 2; ++r) {
        int row = rg * 2 + r, nn = n0 + row;
        float4 v = make_float4(silu_f(acc[r][0]), silu_f(acc[r][1]),
                               silu_f(acc[r][2]), silu_f(acc[r][3]));
        *(float4*)&ss[row * 100 + h4] = v;
        if (nn < N) *(float4*)&sOut[(size_t)nn * 96 + h4] = v;
    }
    __syncthreads();
    float4 b1v = *(const float4*)&bl[h4];
    float4 b2v = *(const float4*)&br[h4];
    float a1[2][4], a2[2][4];
#pragma unroll
    for (int r = 0; r < 2; ++r) {
        a1[r][0] = b1v.x; a1[r][1] = b1v.y; a1[r][2] = b1v.z; a1[r][3] = b1v.w;
        a2[r][0] = b2v.x; a2[r][1] = b2v.y; a2[r][2] = b2v.z; a2[r][3] = b2v.w;
    }
    const float* srow = &ss[rg * 2 * 100];
    for (int k = 0; k < 96; ++k) {
        float4 w1 = *(const float4*)&Wl[k * 96 + h4];
        float4 w2 = *(const float4*)&Wr[k * 96 + h4];
#pragma unroll
        for (int r = 0; r < 2; ++r) {
            float xv = srow[r * 100 + k];
            a1[r][0] += xv * w1.x; a1[r][1] += xv * w1.y; a1[r][2] += xv * w1.z; a1[r][3] += xv * w1.w;
            a2[r][0] += xv * w2.x; a2[r][1] += xv * w2.y; a2[r][2] += xv * w2.z; a2[r][3] += xv * w2.w;
        }
    }
#pragma unroll
    for (int r = 0; r < 2; ++r) {
        int nn = n0 + rg * 2 + r;
        if (nn < N) {
            size_t o = (size_t)(cbase + nn) * 96 + h4;
            *(ushort4*)&xlb[o] = make_ushort4(f2bf(a1[r][0]), f2bf(a1[r][1]), f2bf(a1[r][2]), f2bf(a1[r][3]));
            *(ushort4*)&xrb[o] = make_ushort4(f2bf(a2[r][0]), f2bf(a2[r][1]), f2bf(a2[r][2]), f2bf(a2[r][3]));
        }
    }
}

// q (L) / k,v (P) projections; stride-100 LDS, 32 rows/block.
__global__ __launch_bounds__(192) void qkv_all_kernel(
        const float* __restrict__ s_L, const float* __restrict__ s_P,
        const float* __restrict__ Wq, const float* __restrict__ bq,
        const float* __restrict__ Wk, const float* __restrict__ bk,
        const float* __restrict__ Wv, const float* __restrict__ bv,
        unsigned short* __restrict__ qnb, unsigned short* __restrict__ knb,
        unsigned short* __restrict__ vnb, int N_L, int N_P, int BL) {
    __shared__ float xs[32 * 100];
    int b = blockIdx.x;
    bool isL = b < BL;
    const float* s = isL ? s_L : s_P;
    int N = isL ? N_L : N_P;
    int n0 = (isL ? b : b - BL) * 32;
    int t = threadIdx.x;
    int hg = t % 24, h4 = hg * 4;
    int rg = t / 24;
    for (int i = t; i < 32 * 96; i += 192) {
        int r = i / 96, c = i - r * 96, nn = n0 + r;
        xs[r * 100 + c] = (nn < N) ? s[(size_t)nn * 96 + c] : 0.f;
    }
    __syncthreads();
    const float* srow = &xs[rg * 4 * 100];
    if (isL) {
        float4 bb = *(const float4*)&bq[h4];
        float a1[4][4];
#pragma unroll
        for (int r = 0; r < 4; ++r) { a1[r][0] = bb.x; a1[r][1] = bb.y; a1[r][2] = bb.z; a1[r][3] = bb.w; }
        for (int k = 0; k < 96; ++k) {
            float4 w = *(const float4*)&Wq[k * 96 + h4];
#pragma unroll
            for (int r = 0; r < 4; ++r) {
                float xv = srow[r * 100 + k];
                a1[r][0] += xv * w.x; a1[r][1] += xv * w.y; a1[r][2] += xv * w.z; a1[r][3] += xv * w.w;
            }
        }
#pragma unroll
        for (int r = 0; r < 4; ++r) {
            int nn = n0 + rg * 4 + r;
            if (nn < N)
                *(ushort4*)&qnb[(size_t)nn * 96 + h4] =
                    make_ushort4(f2bf(a1[r][0]), f2bf(a1[r][1]), f2bf(a1[r][2]), f2bf(a1[r][3]));
        }
    } else {
        float4 bb1 = *(const float4*)&bk[h4];
        float4 bb2 = *(const float4*)&bv[h4];
        float a1[4][4], a2[4][4];
#pragma unroll
        for (int r = 0; r < 4; ++r) {
            a1[r][0] = bb1.x; a1[r][1] = bb1.y; a1[r][2] = bb1.z; a1[r][3] = bb1.w;
            a2[r][0] = bb2.x; a2[r][1] = bb2.y; a2[r][2] = bb2.z; a2[r][3] = bb2.w;
        }
        for (int k = 0; k < 96; ++k) {
            float4 w1 = *(const float4*)&Wk[k * 96 + h4];
            float4 w2 = *(const float4*)&Wv[k * 96 + h4];
#pragma unroll
            for (int r = 0; r < 4; ++r) {
                float xv = srow[r * 100 + k];
                a1[r][0] += xv * w1.x; a1[r][1] += xv * w1.y; a1[r][2] += xv * w1.z; a1[r][3] += xv * w1.w;
                a2[r][0] += xv * w2.x; a2[r][1] += xv * w2.y; a2[r][2] += xv * w2.z; a2[r][3] += xv * w2.w;
            }
        }
#pragma unroll
        for (int r = 0; r < 4; ++r) {
            int nn = n0 + rg * 4 + r;
            if (nn < N) {
                *(ushort4*)&knb[(size_t)nn * 96 + h4] =
                    make_ushort4(f2bf(a1[r][0]), f2bf(a1[r][1]), f2bf(a1[r][2]), f2bf(a1[r][3]));
                *(ushort4*)&vnb[(size_t)nn * 96 + h4] =
                    make_ushort4(f2bf(a2[r][0]), f2bf(a2[r][1]), f2bf(a2[r][2]), f2bf(a2[r][3]));
            }
        }
    }
}

// SSM: 8 rows/block; padded LDS (row@100, u@196).
__global__ __launch_bounds__(192) void ssm3_kernel(float* __restrict__ sL,
        const float* __restrict__ Win, const float* __restrict__ b_in,
        const float* __restrict__ Wout, const float* __restrict__ bout, int N) {
    __shared__ float row[8 * 100];
    __shared__ float u[8 * 196];
    int t = threadIdx.x;
    int n0 = blockIdx.x * 8;
    for (int i = t; i < 8 * 96; i += 192) {
        int r = i / 96, c = i - r * 96, nn = n0 + r;
        row[r * 100 + c] = (nn < N) ? sL[(size_t)nn * 96 + c] : 0.f;
    }
    __syncthreads();
    {
        int cg = t % 48, c4 = cg * 4;
        int rg = t / 48;
        float4 bb = *(const float4*)&b_in[c4];
        float a[2][4];
#pragma unroll
        for (int r = 0; r < 2; ++r) { a[r][0] = bb.x; a[r][1] = bb.y; a[r][2] = bb.z; a[r][3] = bb.w; }
        const float* rr = &row[rg * 2 * 100];
        for (int k = 0; k < 96; ++k) {
            float4 w = *(const float4*)&Win[k * 384 + c4];
#pragma unroll
            for (int r = 0; r < 2; ++r) {
                float xv = rr[r * 100 + k];
                a[r][0] += xv * w.x; a[r][1] += xv * w.y; a[r][2] += xv * w.z; a[r][3] += xv * w.w;
            }
        }
#pragma unroll
        for (int r = 0; r < 2; ++r) {
            int ro = rg * 2 + r;
            *(float4*)&u[ro * 196 + c4] = make_float4(silu_f(a[r][0]), silu_f(a[r][1]),
                                                      silu_f(a[r][2]), silu_f(a[r][3]));
        }
    }
    __syncthreads();
    {
        int hg = t % 24, h4 = hg * 4;
        int rg2 = t / 24;
        float4 bb = *(const float4*)&bout[h4];
        float a[4] = {bb.x, bb.y, bb.z, bb.w};
        const float* ur = &u[rg2 * 196];
        for (int j = 0; j < 192; ++j) {
            float4 w = *(const float4*)&Wout[j * 96 + h4];
            float uv = ur[j];
            a[0] += uv * w.x; a[1] += uv * w.y; a[2] += uv * w.z; a[3] += uv * w.w;
        }
        int nn = n0 + rg2;
        if (nn < N) {
            float4 rv = *(const float4*)&row[rg2 * 100 + h4];
            *(float4*)&sL[(size_t)nn * 96 + h4] =
                make_float4(rv.x + a[0], rv.y + a[1], rv.z + a[2], rv.w + a[3]);
        }
    }
}

// head: 32 rows/block; padded LDS.
__global__ __launch_bounds__(192) void head3_kernel(const float* __restrict__ sL,
        const float* __restrict__ W1, const float* __restrict__ b1,
        const float* __restrict__ W2, const float* __restrict__ b2,
        float* __restrict__ out, int N) {
    __shared__ float buf[32 * 100];
    __shared__ float tt[32 * 100];
    int t = threadIdx.x;
    int n0 = blockIdx.x * 32;
    for (int i = t; i < 32 * 96; i += 192) {
        int r = i / 96, c = i - r * 96, nn = n0 + r;
        buf[r * 100 + c] = (nn < N) ? sL[(size_t)nn * 96 + c] : 0.f;
    }
    __syncthreads();
    int hg = t % 24, h4 = hg * 4;
    int rg = t / 24;
    float4 bb = *(const float4*)&b1[h4];
    float a[4][4];
#pragma unroll
    for (int r = 0; r < 4; ++r) { a[r][0] = bb.x; a[r][1] = bb.y; a[r][2] = bb.z; a[r][3] = bb.w; }
    const float* srow = &buf[rg * 4 * 100];
    for (int k = 0; k < 96; ++k) {
        float4 w = *(const float4*)&W1[k * 96 + h4];
#pragma unroll
        for (int r = 0; r < 4; ++r) {
            float xv = srow[r * 100 + k];
            a[r][0] += xv * w.x; a[r][1] += xv * w.y; a[r][2] += xv * w.z; a[r][3] += xv * w.w;
        }
    }
#pragma unroll
    for (int r = 0; r < 4; ++r) {
        int row = rg * 4 + r;
        *(float4*)&tt[row * 100 + h4] = make_float4(silu_f(a[r][0]), silu_f(a[r][1]),
                                                    silu_f(a[r][2]), silu_f(a[r][3]));
    }
    __syncthreads();
    if (t < 96) {
        int r = t / 3, c = t - r * 3;
        float o = b2[c];
        const float* tr = &tt[r * 100];
        for (int j = 0; j < 96; ++j) o += tr[j] * W2[j * 3 + c];
        int nn = n0 + r;
        if (nn < N) out[nn * 3 + c] = o;
    }
}

static inline int cdiv(int a, int b) { return (a + b - 1) / b; }

extern "C" void kernel_launch(void* const* d_in, const int* in_sizes, int n_in,
                              void* d_out, int out_size, void* d_ws, size_t ws_size,
                              hipStream_t stream) {
    const float* x_L   = (const float*)d_in[0];
    const float* pos_L = (const float*)d_in[1];
    const float* x_P   = (const float*)d_in[2];
    const float* pos_P = (const float*)d_in[3];
    const int* edge_L = (const int*)d_in[4];
    const int* edge_P = (const int*)d_in[5];
    const int* csrc   = (const int*)d_in[6];
    const int* ctgt   = (const int*)d_in[7];
    const float *Wemb_L = (const float*)d_in[8],  *bemb_L = (const float*)d_in[9];
    const float *Wl_L = (const float*)d_in[10], *bl_L = (const float*)d_in[11];
    const float *Wr_L = (const float*)d_in[12], *br_L = (const float*)d_in[13];
    const float *We_L = (const float*)d_in[14], *att_L = (const float*)d_in[15], *bias_L = (const float*)d_in[16];
    const float *Wemb_P = (const float*)d_in[17], *bemb_P = (const float*)d_in[18];
    const float *Wl_P = (const float*)d_in[19], *bl_P = (const float*)d_in[20];
    const float *Wr_P = (const float*)d_in[21], *br_P = (const float*)d_in[22];
    const float *We_P = (const float*)d_in[23], *att_P = (const float*)d_in[24], *bias_P = (const float*)d_in[25];
    const float *Win = (const float*)d_in[26], *b_in = (const float*)d_in[27];
    const float *Wout = (const float*)d_in[28], *bout = (const float*)d_in[29];
    const float *Wq = (const float*)d_in[30], *bq = (const float*)d_in[31];
    const float *Wk = (const float*)d_in[32], *bk = (const float*)d_in[33];
    const float *Wv = (const float*)d_in[34], *bv = (const float*)d_in[35];
    const float *W1 = (const float*)d_in[36], *b1 = (const float*)d_in[37];
    const float *W2 = (const float*)d_in[38], *b2 = (const float*)d_in[39];

    const int N_L = in_sizes[1] / 3;
    const int N_P = in_sizes[3] / 3;
    const int E_L = in_sizes[4] / 2;
    const int E_P = in_sizes[5] / 2;
    const int E_X = in_sizes[6];
    const int D_L = in_sizes[0] / N_L;
    const int D_P = in_sizes[2] / N_P;
    const int Ncomb = N_L + N_P;
    const int Ntot = N_L + N_P + N_L;
    const int Etot = E_L + E_P + E_X;
    const int baseX = E_L + E_P;

    // workspace layout
    float* ws = (float*)d_ws;
    float*          s_L    = ws;                                     // N_L*96 f32
    float*          s_P    = s_L + (size_t)N_L * 96;                 // N_P*96 f32
    unsigned short* xrb    = (unsigned short*)(s_P + (size_t)N_P * 96);  // Ncomb*96 bf16
    unsigned short* xlb    = xrb + (size_t)Ncomb * 96;               // Ncomb*96 bf16
    unsigned short* knb    = xlb + (size_t)Ncomb * 96;               // N_P*96 bf16
    unsigned short* vnb    = knb + (size_t)N_P * 96;                 // N_P*96 bf16
    unsigned short* qnb    = vnb + (size_t)N_P * 96;                 // N_L*96 bf16
    unsigned int*   sdp    = (unsigned int*)(qnb + (size_t)N_L * 96);// Etot u32
    float*          clog_s = (float*)(sdp + (size_t)Etot);           // E_X f32
    unsigned int*   T2_L   = (unsigned int*)(clog_s + (size_t)E_X);  // 1024*96
    unsigned int*   T2_P   = T2_L + 1024 * 96;                       // 1024*96
    int*            rowptr = (int*)(T2_P + 1024 * 96);               // Ntot+1
    int*            count  = rowptr + (size_t)Ntot + 1;              // Ntot
    int*            cursor = count + (size_t)Ntot;                   // Ntot
    float*          csc    = (float*)(cursor + (size_t)Ntot);        // 2
    int*            bsum   = (int*)(csc + 2);                        // <=16

    const int BL16 = cdiv(N_L, 16), BP16 = cdiv(N_P, 16);
    const int BL32 = cdiv(N_L, 32), BP32 = cdiv(N_P, 32);

    // tables + combined CSR build
    rbf_table_pack_kernel<<<2048, 96, 0, stream>>>(We_L, We_P, T2_L, T2_P);
    fill_i<<<cdiv(Ntot, 256), 256, 0, stream>>>(count, 0, Ntot);
    hist_all_kernel<<<cdiv(Etot, 256), 256, 0, stream>>>(edge_L + E_L, edge_P + E_P, ctgt,
        count, E_L, E_P, E_X, N_L, N_P);
    scan_blocksum_kernel<<<cdiv(Ntot, 4096), 256, 0, stream>>>(count, bsum, Ntot);
    scan_top_kernel<<<1, 64, 0, stream>>>(bsum, cdiv(Ntot, 4096), csc);
    scan_apply_kernel<<<cdiv(Ntot, 4096), 256, 0, stream>>>(count, bsum, rowptr, cursor, Ntot, Etot);
    pre_all_kernel<<<cdiv(Etot, 256), 256, 0, stream>>>(edge_L, edge_P, csrc, ctgt,
        pos_L, pos_P, cursor, sdp, E_L, E_P, E_X, N_L, N_P);

    // fused embed + gat-linears for both graphs (16 rows/block)
    enc_all_kernel<<<BL16 + BP16, 192, 0, stream>>>(x_L, x_P, Wemb_L, bemb_L, Wemb_P, bemb_P,
        Wl_L, bl_L, Wr_L, br_L, Wl_P, bl_P, Wr_P, br_P,
        s_L, s_P, xlb, xrb, N_L, N_P, D_L, D_P, BL16);

    // combined L+P GAT
    gat_all_kernel<<<cdiv(Ncomb, 8), 256, 0, stream>>>(rowptr, sdp, xlb, xrb, T2_L, T2_P,
        att_L, att_P, bias_L, bias_P, s_L, s_P, N_L, Ncomb);

    // SSM (L)
    ssm3_kernel<<<cdiv(N_L, 8), 192, 0, stream>>>(s_L, Win, b_in, Wout, bout, N_L);

    // cross attention
    qkv_all_kernel<<<BL32 + BP32, 192, 0, stream>>>(s_L, s_P, Wq, bq, Wk, bk, Wv, bv,
        qnb, knb, vnb, N_L, N_P, BL32);
    cross_logit_e_kernel<<<cdiv(E_X, 256), 256, 0, stream>>>(sdp + (size_t)baseX, qnb, knb,
        clog_s, csc, E_X);
    cross_denom_kernel<<<cdiv(E_X, 256), 256, 0, stream>>>(clog_s, csc, E_X);
    cross_apply_v4_kernel<<<cdiv(N_L, 8), 256, 0, stream>>>(rowptr + N_L + N_P, sdp,
        clog_s, vnb, csc, s_L, N_L, baseX);

    // head
    head3_kernel<<<cdiv(N_L, 32), 192, 0, stream>>>(s_L, W1, b1, W2, b2, (float*)d_out, N_L);
}

// Round 13
// 474.423 us; speedup vs baseline: 1.0250x; 1.0250x over previous
//
#include <hip/hip_runtime.h>

__device__ __forceinline__ float silu_f(float x) { return x / (1.f + __expf(-x)); }

__device__ __forceinline__ void atomicMaxF(float* addr, float val) {
    if (val >= 0.f) atomicMax((int*)addr, __float_as_int(val));
    else            atomicMin((unsigned int*)addr, __float_as_uint(val));
}

// f32 -> bf16 (RNE) and back
__device__ __forceinline__ unsigned short f2bf(float x) {
    unsigned int u = __float_as_uint(x);
    return (unsigned short)((u + 0x7fffu + ((u >> 16) & 1u)) >> 16);
}
__device__ __forceinline__ float bf2f(unsigned short h) {
    return __uint_as_float(((unsigned int)h) << 16);
}
__device__ __forceinline__ float bf_lo(unsigned int u) { return __uint_as_float(u << 16); }
__device__ __forceinline__ float bf_hi(unsigned int u) { return __uint_as_float(u & 0xffff0000u); }
__device__ __forceinline__ float bfdot(unsigned int a, unsigned int b) {
    return bf_lo(a) * bf_lo(b) + bf_hi(a) * bf_hi(b);
}

__global__ void fill_i(int* __restrict__ p, int v, int n) {
    int i = blockIdx.x * blockDim.x + threadIdx.x;
    if (i < n) p[i] = v;
}

// combined histogram over [L | P | X] target-node space
__global__ __launch_bounds__(256) void hist_all_kernel(const int* __restrict__ tgtL,
        const int* __restrict__ tgtP, const int* __restrict__ ctgt, int* __restrict__ count,
        int E_L, int E_P, int E_X, int N_L, int N_P) {
    int e = blockIdx.x * blockDim.x + threadIdx.x;
    if (e < E_L) atomicAdd(&count[tgtL[e]], 1);
    else if (e < E_L + E_P) atomicAdd(&count[N_L + tgtP[e - E_L]], 1);
    else if (e < E_L + E_P + E_X) atomicAdd(&count[N_L + N_P + ctgt[e - E_L - E_P]], 1);
}

// ---- hierarchical scan ----
__global__ __launch_bounds__(256) void scan_blocksum_kernel(const int* __restrict__ count,
                                                            int* __restrict__ bsum, int n) {
    int b = blockIdx.x, t = threadIdx.x;
    int base = b * 4096 + t * 16;
    int s = 0;
#pragma unroll
    for (int k = 0; k < 16; ++k) {
        int idx = base + k;
        s += (idx < n) ? count[idx] : 0;
    }
#pragma unroll
    for (int off = 1; off < 64; off <<= 1) s += __shfl_xor(s, off, 64);
    __shared__ int ws[4];
    int lane = t & 63, wid = t >> 6;
    if (lane == 0) ws[wid] = s;
    __syncthreads();
    if (t == 0) bsum[b] = ws[0] + ws[1] + ws[2] + ws[3];
}

__global__ void scan_top_kernel(int* __restrict__ bsum, int nb, float* __restrict__ csc) {
    if (threadIdx.x == 0) {
        int run = 0;
        for (int i = 0; i < nb; ++i) { int c = bsum[i]; bsum[i] = run; run += c; }
        csc[0] = -3.4e38f; csc[1] = 0.f;
    }
}

__global__ __launch_bounds__(256) void scan_apply_kernel(const int* __restrict__ count,
        const int* __restrict__ bsum, int* __restrict__ rowptr, int* __restrict__ cursor,
        int n, int E) {
    int b = blockIdx.x, t = threadIdx.x;
    int base = b * 4096 + t * 16;
    int v[16];
    int s = 0;
#pragma unroll
    for (int k = 0; k < 16; ++k) {
        int idx = base + k;
        v[k] = (idx < n) ? count[idx] : 0;
        s += v[k];
    }
    int lane = t & 63, wid = t >> 6;
    int inc = s;
#pragma unroll
    for (int off = 1; off < 64; off <<= 1) {
        int o = __shfl_up(inc, off, 64);
        if (lane >= off) inc += o;
    }
    __shared__ int ws[4];
    if (lane == 63) ws[wid] = inc;
    __syncthreads();
    int woff = 0;
    for (int w = 0; w < wid; ++w) woff += ws[w];
    int prefix = bsum[b] + woff + (inc - s);
#pragma unroll
    for (int k = 0; k < 16; ++k) {
        int idx = base + k;
        if (idx < n) { rowptr[idx] = prefix; cursor[idx] = prefix; prefix += v[k]; }
    }
    if (b == 0 && t == 0) rowptr[n] = E;
}

// combined CSR fill, 4-byte packed payloads
__global__ __launch_bounds__(256) void pre_all_kernel(const int* __restrict__ eL,
        const int* __restrict__ eP, const int* __restrict__ csrc, const int* __restrict__ ctgt,
        const float* __restrict__ posL, const float* __restrict__ posP,
        int* __restrict__ cursor, unsigned int* __restrict__ sdp,
        int E_L, int E_P, int E_X, int N_L, int N_P) {
    int e = blockIdx.x * blockDim.x + threadIdx.x;
    if (e >= E_L + E_P + E_X) return;
    unsigned int pack;
    int node;
    if (e < E_L + E_P) {
        const int* ed; const float* pos; int idx, E, nbase;
        if (e < E_L) { ed = eL; pos = posL; idx = e; E = E_L; nbase = 0; }
        else         { ed = eP; pos = posP; idx = e - E_L; E = E_P; nbase = N_L; }
        int si = ed[idx], ti = ed[E + idx];
        node = nbase + ti;
        float dx = pos[si * 3 + 0] - pos[ti * 3 + 0];
        float dy = pos[si * 3 + 1] - pos[ti * 3 + 1];
        float dz = pos[si * 3 + 2] - pos[ti * 3 + 2];
        float dist = sqrtf(dx * dx + dy * dy + dz * dz);
        int dq = min((int)(dist * 4096.f), 65535);
        pack = (unsigned int)(si + nbase) | ((unsigned int)dq << 16);
    } else {
        int idx = e - E_L - E_P;
        int ti = ctgt[idx];
        pack = (unsigned int)csrc[idx] | ((unsigned int)ti << 16);
        node = N_L + N_P + ti;
    }
    int p = atomicAdd(&cursor[node], 1);
    sdp[p] = pack;
}

// packed RBF@We table
__global__ __launch_bounds__(96) void rbf_table_pack_kernel(const float* __restrict__ We_L,
        const float* __restrict__ We_P, unsigned int* __restrict__ T2_L,
        unsigned int* __restrict__ T2_P) {
    int b = blockIdx.x;
    const float* We = (b < 1024) ? We_L : We_P;
    unsigned int* T2 = (b < 1024) ? T2_L : T2_P;
    int i = (b < 1024) ? b : b - 1024;
    int h = threadIdx.x;
    float d0 = (float)i * 0.015625f, d1 = (float)(i + 1) * 0.015625f;
    float a0 = 0.f, a1 = 0.f;
#pragma unroll
    for (int g = 0; g < 16; ++g) {
        float w = We[g * 96 + h];
        float t0 = d0 - 0.66666667f * (float)g;
        float t1 = d1 - 0.66666667f * (float)g;
        a0 += __expf(-1.125f * t0 * t0) * w;
        a1 += __expf(-1.125f * t1 * t1) * w;
    }
    T2[i * 96 + h] = (unsigned int)f2bf(a0) | ((unsigned int)f2bf(a1 - a0) << 16);
}

// Combined L+P GATv2: half-wave per combined node; xr bf16 (round-10 version).
__global__ __launch_bounds__(256) void gat_all_kernel(const int* __restrict__ rowptr,
        const unsigned int* __restrict__ sdp, const unsigned short* __restrict__ xlb,
        const unsigned short* __restrict__ xrb,
        const unsigned int* __restrict__ T2_L, const unsigned int* __restrict__ T2_P,
        const float* __restrict__ att_L, const float* __restrict__ att_P,
        const float* __restrict__ bias_L, const float* __restrict__ bias_P,
        float* __restrict__ s_L, float* __restrict__ s_P, int N_L, int Ncomb) {
    int tid = threadIdx.x;
    int l = tid & 31;
    int n = blockIdx.x * 8 + (tid >> 5);
    if (n >= Ncomb) return;
    bool isL = n < N_L;
    const unsigned int* T2 = isL ? T2_L : T2_P;
    const float* att = isL ? att_L : att_P;
    const float* bias = isL ? bias_L : bias_P;
    float* srow = isL ? (s_L + (size_t)n * 96) : (s_P + (size_t)(n - N_L) * 96);
    float att0 = att[l], att1 = att[32 + l], att2 = att[64 + l];
    size_t nb = (size_t)n * 96;
    float xr0 = bf2f(xrb[nb + l]), xr1 = bf2f(xrb[nb + 32 + l]), xr2 = bf2f(xrb[nb + 64 + l]);
    int beg = rowptr[n], end = rowptr[n + 1];
    float m = -3.4e38f, d = 0.f, a0 = 0.f, a1 = 0.f, a2 = 0.f;
    for (int j = beg; j < end; j += 4) {
        unsigned int tp0[4], tp1[4], tp2[4];
        unsigned short xs0[4], xs1[4], xs2[4];
        float ff[4];
#pragma unroll
        for (int k = 0; k < 4; ++k) {
            int jj = min(j + k, end - 1);
            unsigned int u = sdp[jj];
            int src = (int)(u & 0xffffu);
            int dq = (int)(u >> 16);
            int i = dq >> 6;
            ff[k] = (float)(dq & 63) * 0.015625f;
            const unsigned int* tr = T2 + (size_t)i * 96;
            tp0[k] = tr[l]; tp1[k] = tr[32 + l]; tp2[k] = tr[64 + l];
            const unsigned short* xp = xlb + (size_t)src * 96;
            xs0[k] = xp[l]; xs1[k] = xp[32 + l]; xs2[k] = xp[64 + l];
        }
        float y0[4], y1[4], y2[4], lt[4];
#pragma unroll
        for (int k = 0; k < 4; ++k) {
            y0[k] = bf2f(xs0[k]); y1[k] = bf2f(xs1[k]); y2[k] = bf2f(xs2[k]);
            float v0 = y0[k] + xr0 + bf_lo(tp0[k]) + ff[k] * bf_hi(tp0[k]);
            float v1 = y1[k] + xr1 + bf_lo(tp1[k]) + ff[k] * bf_hi(tp1[k]);
            float v2 = y2[k] + xr2 + bf_lo(tp2[k]) + ff[k] * bf_hi(tp2[k]);
            v0 = fmaxf(v0, 0.f) + 0.2f * fminf(v0, 0.f);
            v1 = fmaxf(v1, 0.f) + 0.2f * fminf(v1, 0.f);
            v2 = fmaxf(v2, 0.f) + 0.2f * fminf(v2, 0.f);
            float t = v0 * att0 + v1 * att1 + v2 * att2;
#pragma unroll
            for (int off = 1; off < 32; off <<= 1) t += __shfl_xor(t, off, 64);
            lt[k] = (j + k < end) ? t : -3.4e38f;
        }
        float bm = fmaxf(fmaxf(lt[0], lt[1]), fmaxf(lt[2], lt[3]));
        float nm = fmaxf(m, bm);
        float sc = __expf(m - nm);
        d *= sc; a0 *= sc; a1 *= sc; a2 *= sc;
#pragma unroll
        for (int k = 0; k < 4; ++k) {
            float w = __expf(lt[k] - nm);
            d += w;
            a0 += w * y0[k]; a1 += w * y1[k]; a2 += w * y2[k];
        }
        m = nm;
    }
    float agg0 = (d > 0.f) ? a0 / d : 0.f;
    float agg1 = (d > 0.f) ? a1 / d : 0.f;
    float agg2 = (d > 0.f) ? a2 / d : 0.f;
    srow[l]      += silu_f(agg0 + bias[l]);
    srow[32 + l] += silu_f(agg1 + bias[32 + l]);
    srow[64 + l] += silu_f(agg2 + bias[64 + l]);
}

// edge-parallel cross logits
__global__ __launch_bounds__(256) void cross_logit_e_kernel(const unsigned int* __restrict__ sdX,
        const unsigned short* __restrict__ qnb, const unsigned short* __restrict__ knb,
        float* __restrict__ clog_s, float* __restrict__ csc, int E) {
    int e = blockIdx.x * blockDim.x + threadIdx.x;
    float logit = -3.4e38f;
    if (e < E) {
        unsigned int u = sdX[e];
        int src = (int)(u & 0xffffu);
        int tgt = (int)(u >> 16);
        const uint4* q4 = (const uint4*)(qnb + (size_t)tgt * 96);
        const uint4* k4 = (const uint4*)(knb + (size_t)src * 96);
        float acc = 0.f;
#pragma unroll
        for (int i = 0; i < 12; ++i) {
            uint4 qa = q4[i], ka = k4[i];
            acc += bfdot(qa.x, ka.x) + bfdot(qa.y, ka.y) + bfdot(qa.z, ka.z) + bfdot(qa.w, ka.w);
        }
        logit = acc * 0.125f;
        clog_s[e] = logit;
    }
    __shared__ float red[256];
    red[threadIdx.x] = logit; __syncthreads();
    for (int s = 128; s > 0; s >>= 1) {
        if (threadIdx.x < s) red[threadIdx.x] = fmaxf(red[threadIdx.x], red[threadIdx.x + s]);
        __syncthreads();
    }
    if (threadIdx.x == 0) atomicMaxF(&csc[0], red[0]);
}

__global__ __launch_bounds__(256) void cross_denom_kernel(const float* __restrict__ clog_s,
                                                          float* __restrict__ csc, int E) {
    int e = blockIdx.x * blockDim.x + threadIdx.x;
    float a = 0.f;
    float mg = csc[0];
    if (e < E) a = __expf(clog_s[e] - mg);
    __shared__ float red[256];
    red[threadIdx.x] = a; __syncthreads();
    for (int s = 128; s > 0; s >>= 1) {
        if (threadIdx.x < s) red[threadIdx.x] += red[threadIdx.x + s];
        __syncthreads();
    }
    if (threadIdx.x == 0) atomicAdd(&csc[1], red[0]);
}

// cross apply: half-wave per L node (round-10 version)
__global__ __launch_bounds__(256) void cross_apply_v4_kernel(const int* __restrict__ rowptr,
        const unsigned int* __restrict__ sdp, const float* __restrict__ clog_s,
        const unsigned short* __restrict__ vnb, const float* __restrict__ csc,
        float* __restrict__ sL, int N, int baseX) {
    int tid = threadIdx.x;
    int l = tid & 31;
    int n = blockIdx.x * 8 + (tid >> 5);
    if (n >= N) return;
    int beg = rowptr[n], end = rowptr[n + 1];
    if (beg == end) return;
    float M = csc[0], invD = 1.f / csc[1];
    float a0 = 0.f, a1 = 0.f, a2 = 0.f;
    for (int j = beg; j < end; j += 4) {
        unsigned short v0[4], v1[4], v2[4]; float w[4];
#pragma unroll
        for (int k = 0; k < 4; ++k) {
            int jj = min(j + k, end - 1);
            int src = (int)(sdp[jj] & 0xffffu);
            const unsigned short* vp = vnb + (size_t)src * 96;
            v0[k] = vp[l]; v1[k] = vp[32 + l]; v2[k] = vp[64 + l];
            w[k] = (j + k < end) ? __expf(clog_s[jj - baseX] - M) : 0.f;
        }
#pragma unroll
        for (int k = 0; k < 4; ++k) {
            a0 += w[k] * bf2f(v0[k]); a1 += w[k] * bf2f(v1[k]); a2 += w[k] * bf2f(v2[k]);
        }
    }
    size_t nb = (size_t)n * 96;
    sL[nb + l]      += a0 * invD;
    sL[nb + 32 + l] += a1 * invD;
    sL[nb + 64 + l] += a2 * invD;
}

// ---------- vectorized dense kernels ----------

// fused embed + dual GAT-linear; 48 rows/block, 6 rows x 4 cols per thread.
__global__ __launch_bounds__(192) void enc_all_kernel(
        const float* __restrict__ x_L, const float* __restrict__ x_P,
        const float* __restrict__ WembL, const float* __restrict__ bembL,
        const float* __restrict__ WembP, const float* __restrict__ bembP,
        const float* __restrict__ WlL, const float* __restrict__ blL,
        const float* __restrict__ WrL, const float* __restrict__ brL,
        const float* __restrict__ WlP, const float* __restrict__ blP,
        const float* __restrict__ WrP, const float* __restrict__ brP,
        float* __restrict__ s_L, float* __restrict__ s_P,
        unsigned short* __restrict__ xlb, unsigned short* __restrict__ xrb,
        int N_L, int N_P, int D_L, int D_P, int BL) {
    __shared__ float xs[48 * 167];
    __shared__ float ss[48 * 100];
    int b = blockIdx.x;
    bool isL = b < BL;
    const float* x    = isL ? x_L : x_P;
    const float* Wemb = isL ? WembL : WembP;
    const float* bemb = isL ? bembL : bembP;
    const float* Wl   = isL ? WlL : WlP;
    const float* bl   = isL ? blL : blP;
    const float* Wr   = isL ? WrL : WrP;
    const float* br   = isL ? brL : brP;
    float* sOut = isL ? s_L : s_P;
    int N = isL ? N_L : N_P;
    int D = isL ? D_L : D_P;
    int n0 = (isL ? b : b - BL) * 48;
    int cbase = isL ? 0 : N_L;
    int t = threadIdx.x;
    int hg = t % 24, h4 = hg * 4;
    int rg = t / 24;  // 0..7, rows rg*6 .. rg*6+5
    for (int i = t; i < 48 * D; i += 192) {
        int r = i / D, dd = i - r * D, nn = n0 + r;
        xs[i] = (nn < N) ? x[(size_t)nn * D + dd] : 0.f;
    }
    __syncthreads();
    float4 be = *(const float4*)&bemb[h4];
    float acc[6][4];
#pragma unroll
    for (int r = 0; r < 6; ++r) { acc[r][0] = be.x; acc[r][1] = be.y; acc[r][2] = be.z; acc[r][3] = be.w; }
    const float* xrow = &xs[rg * 6 * D];
    for (int dd = 0; dd < D; ++dd) {
        float4 w = *(const float4*)&Wemb[dd * 96 + h4];
#pragma unroll
        for (int r = 0; r < 6; ++r) {
            float xv = xrow[r * D + dd];
            acc[r][0] += xv * w.x; acc[r][1] += xv * w.y;
            acc[r][2] += xv * w.z; acc[r][3] += xv * w.w;
        }
    }
#pragma unroll
    for (int r = 0; r < 6; ++r) {
        int row = rg * 6 + r, nn = n0 + row;
        float4 v = make_float4(silu_f(acc[r][0]), silu_f(acc[r][1]),
                               silu_f(acc[r][2]), silu_f(acc[r][3]));
        *(float4*)&ss[row * 100 + h4] = v;
        if (nn < N) *(float4*)&sOut[(size_t)nn * 96 + h4] = v;
    }
    __syncthreads();
    float4 b1v = *(const float4*)&bl[h4];
    float4 b2v = *(const float4*)&br[h4];
    float a1[6][4], a2[6][4];
#pragma unroll
    for (int r = 0; r < 6; ++r) {
        a1[r][0] = b1v.x; a1[r][1] = b1v.y; a1[r][2] = b1v.z; a1[r][3] = b1v.w;
        a2[r][0] = b2v.x; a2[r][1] = b2v.y; a2[r][2] = b2v.z; a2[r][3] = b2v.w;
    }
    const float* srow = &ss[rg * 6 * 100];
    for (int k = 0; k < 96; ++k) {
        float4 w1 = *(const float4*)&Wl[k * 96 + h4];
        float4 w2 = *(const float4*)&Wr[k * 96 + h4];
#pragma unroll
        for (int r = 0; r < 6; ++r) {
            float xv = srow[r * 100 + k];
            a1[r][0] += xv * w1.x; a1[r][1] += xv * w1.y; a1[r][2] += xv * w1.z; a1[r][3] += xv * w1.w;
            a2[r][0] += xv * w2.x; a2[r][1] += xv * w2.y; a2[r][2] += xv * w2.z; a2[r][3] += xv * w2.w;
        }
    }
#pragma unroll
    for (int r = 0; r < 6; ++r) {
        int nn = n0 + rg * 6 + r;
        if (nn < N) {
            size_t o = (size_t)(cbase + nn) * 96 + h4;
            *(ushort4*)&xlb[o] = make_ushort4(f2bf(a1[r][0]), f2bf(a1[r][1]), f2bf(a1[r][2]), f2bf(a1[r][3]));
            *(ushort4*)&xrb[o] = make_ushort4(f2bf(a2[r][0]), f2bf(a2[r][1]), f2bf(a2[r][2]), f2bf(a2[r][3]));
        }
    }
}

// q (L) / k,v (P) projections; 32 rows/block, 4h x 4 rows per thread (round-10 version).
__global__ __launch_bounds__(192) void qkv_all_kernel(
        const float* __restrict__ s_L, const float* __restrict__ s_P,
        const float* __restrict__ Wq, const float* __restrict__ bq,
        const float* __restrict__ Wk, const float* __restrict__ bk,
        const float* __restrict__ Wv, const float* __restrict__ bv,
        unsigned short* __restrict__ qnb, unsigned short* __restrict__ knb,
        unsigned short* __restrict__ vnb, int N_L, int N_P, int BL) {
    __shared__ float xs[32 * 96];
    int b = blockIdx.x;
    bool isL = b < BL;
    const float* s = isL ? s_L : s_P;
    int N = isL ? N_L : N_P;
    int n0 = (isL ? b : b - BL) * 32;
    int t = threadIdx.x;
    int hg = t % 24, h4 = hg * 4;
    int rg = t / 24;
    for (int i = t; i < 32 * 96; i += 192) {
        int r = i / 96, c = i - r * 96, nn = n0 + r;
        xs[i] = (nn < N) ? s[(size_t)nn * 96 + c] : 0.f;
    }
    __syncthreads();
    const float* srow = &xs[rg * 4 * 96];
    if (isL) {
        float4 bb = *(const float4*)&bq[h4];
        float a1[4][4];
#pragma unroll
        for (int r = 0; r < 4; ++r) { a1[r][0] = bb.x; a1[r][1] = bb.y; a1[r][2] = bb.z; a1[r][3] = bb.w; }
        for (int k = 0; k < 96; ++k) {
            float4 w = *(const float4*)&Wq[k * 96 + h4];
#pragma unroll
            for (int r = 0; r < 4; ++r) {
                float xv = srow[r * 96 + k];
                a1[r][0] += xv * w.x; a1[r][1] += xv * w.y; a1[r][2] += xv * w.z; a1[r][3] += xv * w.w;
            }
        }
#pragma unroll
        for (int r = 0; r < 4; ++r) {
            int nn = n0 + rg * 4 + r;
            if (nn < N)
                *(ushort4*)&qnb[(size_t)nn * 96 + h4] =
                    make_ushort4(f2bf(a1[r][0]), f2bf(a1[r][1]), f2bf(a1[r][2]), f2bf(a1[r][3]));
        }
    } else {
        float4 bb1 = *(const float4*)&bk[h4];
        float4 bb2 = *(const float4*)&bv[h4];
        float a1[4][4], a2[4][4];
#pragma unroll
        for (int r = 0; r < 4; ++r) {
            a1[r][0] = bb1.x; a1[r][1] = bb1.y; a1[r][2] = bb1.z; a1[r][3] = bb1.w;
            a2[r][0] = bb2.x; a2[r][1] = bb2.y; a2[r][2] = bb2.z; a2[r][3] = bb2.w;
        }
        for (int k = 0; k < 96; ++k) {
            float4 w1 = *(const float4*)&Wk[k * 96 + h4];
            float4 w2 = *(const float4*)&Wv[k * 96 + h4];
#pragma unroll
            for (int r = 0; r < 4; ++r) {
                float xv = srow[r * 96 + k];
                a1[r][0] += xv * w1.x; a1[r][1] += xv * w1.y; a1[r][2] += xv * w1.z; a1[r][3] += xv * w1.w;
                a2[r][0] += xv * w2.x; a2[r][1] += xv * w2.y; a2[r][2] += xv * w2.z; a2[r][3] += xv * w2.w;
            }
        }
#pragma unroll
        for (int r = 0; r < 4; ++r) {
            int nn = n0 + rg * 4 + r;
            if (nn < N) {
                *(ushort4*)&knb[(size_t)nn * 96 + h4] =
                    make_ushort4(f2bf(a1[r][0]), f2bf(a1[r][1]), f2bf(a1[r][2]), f2bf(a1[r][3]));
                *(ushort4*)&vnb[(size_t)nn * 96 + h4] =
                    make_ushort4(f2bf(a2[r][0]), f2bf(a2[r][1]), f2bf(a2[r][2]), f2bf(a2[r][3]));
            }
        }
    }
}

// SSM: 8 rows/block (round-10 version).
__global__ __launch_bounds__(192) void ssm3_kernel(float* __restrict__ sL,
        const float* __restrict__ Win, const float* __restrict__ b_in,
        const float* __restrict__ Wout, const float* __restrict__ bout, int N) {
    __shared__ float row[8 * 96];
    __shared__ float u[8 * 192];
    int t = threadIdx.x;
    int n0 = blockIdx.x * 8;
    for (int i = t; i < 8 * 96; i += 192) {
        int r = i / 96, c = i - r * 96, nn = n0 + r;
        row[i] = (nn < N) ? sL[(size_t)nn * 96 + c] : 0.f;
    }
    __syncthreads();
    {
        int cg = t % 48, c4 = cg * 4;
        int rg = t / 48;
        float4 bb = *(const float4*)&b_in[c4];
        float a[2][4];
#pragma unroll
        for (int r = 0; r < 2; ++r) { a[r][0] = bb.x; a[r][1] = bb.y; a[r][2] = bb.z; a[r][3] = bb.w; }
        const float* rr = &row[rg * 2 * 96];
        for (int k = 0; k < 96; ++k) {
            float4 w = *(const float4*)&Win[k * 384 + c4];
#pragma unroll
            for (int r = 0; r < 2; ++r) {
                float xv = rr[r * 96 + k];
                a[r][0] += xv * w.x; a[r][1] += xv * w.y; a[r][2] += xv * w.z; a[r][3] += xv * w.w;
            }
        }
#pragma unroll
        for (int r = 0; r < 2; ++r) {
            int ro = rg * 2 + r;
            u[ro * 192 + c4 + 0] = silu_f(a[r][0]);
            u[ro * 192 + c4 + 1] = silu_f(a[r][1]);
            u[ro * 192 + c4 + 2] = silu_f(a[r][2]);
            u[ro * 192 + c4 + 3] = silu_f(a[r][3]);
        }
    }
    __syncthreads();
    {
        int hg = t % 24, h4 = hg * 4;
        int rg2 = t / 24;
        float4 bb = *(const float4*)&bout[h4];
        float a[4] = {bb.x, bb.y, bb.z, bb.w};
        const float* ur = &u[rg2 * 192];
        for (int j = 0; j < 192; ++j) {
            float4 w = *(const float4*)&Wout[j * 96 + h4];
            float uv = ur[j];
            a[0] += uv * w.x; a[1] += uv * w.y; a[2] += uv * w.z; a[3] += uv * w.w;
        }
        int nn = n0 + rg2;
        if (nn < N) {
            float4 rv = *(const float4*)&row[rg2 * 96 + h4];
            *(float4*)&sL[(size_t)nn * 96 + h4] =
                make_float4(rv.x + a[0], rv.y + a[1], rv.z + a[2], rv.w + a[3]);
        }
    }
}

// head: 32 rows/block (round-10 version).
__global__ __launch_bounds__(192) void head3_kernel(const float* __restrict__ sL,
        const float* __restrict__ W1, const float* __restrict__ b1,
        const float* __restrict__ W2, const float* __restrict__ b2,
        float* __restrict__ out, int N) {
    __shared__ float buf[32 * 96];
    __shared__ float tt[32 * 96];
    int t = threadIdx.x;
    int n0 = blockIdx.x * 32;
    for (int i = t; i < 32 * 96; i += 192) {
        int r = i / 96, c = i - r * 96, nn = n0 + r;
        buf[i] = (nn < N) ? sL[(size_t)nn * 96 + c] : 0.f;
    }
    __syncthreads();
    int hg = t % 24, h4 = hg * 4;
    int rg = t / 24;
    float4 bb = *(const float4*)&b1[h4];
    float a[4][4];
#pragma unroll
    for (int r = 0; r < 4; ++r) { a[r][0] = bb.x; a[r][1] = bb.y; a[r][2] = bb.z; a[r][3] = bb.w; }
    const float* srow = &buf[rg * 4 * 96];
    for (int k = 0; k < 96; ++k) {
        float4 w = *(const float4*)&W1[k * 96 + h4];
#pragma unroll
        for (int r = 0; r < 4; ++r) {
            float xv = srow[r * 96 + k];
            a[r][0] += xv * w.x; a[r][1] += xv * w.y; a[r][2] += xv * w.z; a[r][3] += xv * w.w;
        }
    }
#pragma unroll
    for (int r = 0; r < 4; ++r) {
        int row = rg * 4 + r;
        *(float4*)&tt[row * 96 + h4] = make_float4(silu_f(a[r][0]), silu_f(a[r][1]),
                                                   silu_f(a[r][2]), silu_f(a[r][3]));
    }
    __syncthreads();
    if (t < 96) {
        int r = t / 3, c = t - r * 3;
        float o = b2[c];
        const float* tr = &tt[r * 96];
        for (int j = 0; j < 96; ++j) o += tr[j] * W2[j * 3 + c];
        int nn = n0 + r;
        if (nn < N) out[nn * 3 + c] = o;
    }
}

static inline int cdiv(int a, int b) { return (a + b - 1) / b; }

extern "C" void kernel_launch(void* const* d_in, const int* in_sizes, int n_in,
                              void* d_out, int out_size, void* d_ws, size_t ws_size,
                              hipStream_t stream) {
    const float* x_L   = (const float*)d_in[0];
    const float* pos_L = (const float*)d_in[1];
    const float* x_P   = (const float*)d_in[2];
    const float* pos_P = (const float*)d_in[3];
    const int* edge_L = (const int*)d_in[4];
    const int* edge_P = (const int*)d_in[5];
    const int* csrc   = (const int*)d_in[6];
    const int* ctgt   = (const int*)d_in[7];
    const float *Wemb_L = (const float*)d_in[8],  *bemb_L = (const float*)d_in[9];
    const float *Wl_L = (const float*)d_in[10], *bl_L = (const float*)d_in[11];
    const float *Wr_L = (const float*)d_in[12], *br_L = (const float*)d_in[13];
    const float *We_L = (const float*)d_in[14], *att_L = (const float*)d_in[15], *bias_L = (const float*)d_in[16];
    const float *Wemb_P = (const float*)d_in[17], *bemb_P = (const float*)d_in[18];
    const float *Wl_P = (const float*)d_in[19], *bl_P = (const float*)d_in[20];
    const float *Wr_P = (const float*)d_in[21], *br_P = (const float*)d_in[22];
    const float *We_P = (const float*)d_in[23], *att_P = (const float*)d_in[24], *bias_P = (const float*)d_in[25];
    const float *Win = (const float*)d_in[26], *b_in = (const float*)d_in[27];
    const float *Wout = (const float*)d_in[28], *bout = (const float*)d_in[29];
    const float *Wq = (const float*)d_in[30], *bq = (const float*)d_in[31];
    const float *Wk = (const float*)d_in[32], *bk = (const float*)d_in[33];
    const float *Wv = (const float*)d_in[34], *bv = (const float*)d_in[35];
    const float *W1 = (const float*)d_in[36], *b1 = (const float*)d_in[37];
    const float *W2 = (const float*)d_in[38], *b2 = (const float*)d_in[39];

    const int N_L = in_sizes[1] / 3;
    const int N_P = in_sizes[3] / 3;
    const int E_L = in_sizes[4] / 2;
    const int E_P = in_sizes[5] / 2;
    const int E_X = in_sizes[6];
    const int D_L = in_sizes[0] / N_L;
    const int D_P = in_sizes[2] / N_P;
    const int Ncomb = N_L + N_P;
    const int Ntot = N_L + N_P + N_L;
    const int Etot = E_L + E_P + E_X;
    const int baseX = E_L + E_P;

    // workspace layout
    float* ws = (float*)d_ws;
    float*          s_L    = ws;                                     // N_L*96 f32
    float*          s_P    = s_L + (size_t)N_L * 96;                 // N_P*96 f32
    unsigned short* xrb    = (unsigned short*)(s_P + (size_t)N_P * 96);  // Ncomb*96 bf16
    unsigned short* xlb    = xrb + (size_t)Ncomb * 96;               // Ncomb*96 bf16
    unsigned short* knb    = xlb + (size_t)Ncomb * 96;               // N_P*96 bf16
    unsigned short* vnb    = knb + (size_t)N_P * 96;                 // N_P*96 bf16
    unsigned short* qnb    = vnb + (size_t)N_P * 96;                 // N_L*96 bf16
    unsigned int*   sdp    = (unsigned int*)(qnb + (size_t)N_L * 96);// Etot u32
    float*          clog_s = (float*)(sdp + (size_t)Etot);           // E_X f32
    unsigned int*   T2_L   = (unsigned int*)(clog_s + (size_t)E_X);  // 1024*96
    unsigned int*   T2_P   = T2_L + 1024 * 96;                       // 1024*96
    int*            rowptr = (int*)(T2_P + 1024 * 96);               // Ntot+1
    int*            count  = rowptr + (size_t)Ntot + 1;              // Ntot
    int*            cursor = count + (size_t)Ntot;                   // Ntot
    float*          csc    = (float*)(cursor + (size_t)Ntot);        // 2
    int*            bsum   = (int*)(csc + 2);                        // <=16

    const int BL48 = cdiv(N_L, 48), BP48 = cdiv(N_P, 48);
    const int BL32 = cdiv(N_L, 32), BP32 = cdiv(N_P, 32);

    // tables + combined CSR build
    rbf_table_pack_kernel<<<2048, 96, 0, stream>>>(We_L, We_P, T2_L, T2_P);
    fill_i<<<cdiv(Ntot, 256), 256, 0, stream>>>(count, 0, Ntot);
    hist_all_kernel<<<cdiv(Etot, 256), 256, 0, stream>>>(edge_L + E_L, edge_P + E_P, ctgt,
        count, E_L, E_P, E_X, N_L, N_P);
    scan_blocksum_kernel<<<cdiv(Ntot, 4096), 256, 0, stream>>>(count, bsum, Ntot);
    scan_top_kernel<<<1, 64, 0, stream>>>(bsum, cdiv(Ntot, 4096), csc);
    scan_apply_kernel<<<cdiv(Ntot, 4096), 256, 0, stream>>>(count, bsum, rowptr, cursor, Ntot, Etot);
    pre_all_kernel<<<cdiv(Etot, 256), 256, 0, stream>>>(edge_L, edge_P, csrc, ctgt,
        pos_L, pos_P, cursor, sdp, E_L, E_P, E_X, N_L, N_P);

    // fused embed + gat-linears for both graphs (48 rows/block)
    enc_all_kernel<<<BL48 + BP48, 192, 0, stream>>>(x_L, x_P, Wemb_L, bemb_L, Wemb_P, bemb_P,
        Wl_L, bl_L, Wr_L, br_L, Wl_P, bl_P, Wr_P, br_P,
        s_L, s_P, xlb, xrb, N_L, N_P, D_L, D_P, BL48);

    // combined L+P GAT
    gat_all_kernel<<<cdiv(Ncomb, 8), 256, 0, stream>>>(rowptr, sdp, xlb, xrb, T2_L, T2_P,
        att_L, att_P, bias_L, bias_P, s_L, s_P, N_L, Ncomb);

    // SSM (L)
    ssm3_kernel<<<cdiv(N_L, 8), 192, 0, stream>>>(s_L, Win, b_in, Wout, bout, N_L);

    // cross attention
    qkv_all_kernel<<<BL32 + BP32, 192, 0, stream>>>(s_L, s_P, Wq, bq, Wk, bk, Wv, bv,
        qnb, knb, vnb, N_L, N_P, BL32);
    cross_logit_e_kernel<<<cdiv(E_X, 256), 256, 0, stream>>>(sdp + (size_t)baseX, qnb, knb,
        clog_s, csc, E_X);
    cross_denom_kernel<<<cdiv(E_X, 256), 256, 0, stream>>>(clog_s, csc, E_X);
    cross_apply_v4_kernel<<<cdiv(N_L, 8), 256, 0, stream>>>(rowptr + N_L + N_P, sdp,
        clog_s, vnb, csc, s_L, N_L, baseX);

    // head
    head3_kernel<<<cdiv(N_L, 32), 192, 0, stream>>>(s_L, W1, b1, W2, b2, (float*)d_out, N_L);
}

// Round 14
// 469.793 us; speedup vs baseline: 1.0351x; 1.0099x over previous
//
#include <hip/hip_runtime.h>

__device__ __forceinline__ float silu_f(float x) { return x / (1.f + __expf(-x)); }

__device__ __forceinline__ void atomicMaxF(float* addr, float val) {
    if (val >= 0.f) atomicMax((int*)addr, __float_as_int(val));
    else            atomicMin((unsigned int*)addr, __float_as_uint(val));
}

// f32 -> bf16 (RNE) and back
__device__ __forceinline__ unsigned short f2bf(float x) {
    unsigned int u = __float_as_uint(x);
    return (unsigned short)((u + 0x7fffu + ((u >> 16) & 1u)) >> 16);
}
__device__ __forceinline__ float bf2f(unsigned short h) {
    return __uint_as_float(((unsigned int)h) << 16);
}
__device__ __forceinline__ float bf_lo(unsigned int u) { return __uint_as_float(u << 16); }
__device__ __forceinline__ float bf_hi(unsigned int u) { return __uint_as_float(u & 0xffff0000u); }
__device__ __forceinline__ float bfdot(unsigned int a, unsigned int b) {
    return bf_lo(a) * bf_lo(b) + bf_hi(a) * bf_hi(b);
}

__global__ void fill_i(int* __restrict__ p, int v, int n) {
    int i = blockIdx.x * blockDim.x + threadIdx.x;
    if (i < n) p[i] = v;
}

// combined histogram over [L | P | X] target-node space
__global__ __launch_bounds__(256) void hist_all_kernel(const int* __restrict__ tgtL,
        const int* __restrict__ tgtP, const int* __restrict__ ctgt, int* __restrict__ count,
        int E_L, int E_P, int E_X, int N_L, int N_P) {
    int e = blockIdx.x * blockDim.x + threadIdx.x;
    if (e < E_L) atomicAdd(&count[tgtL[e]], 1);
    else if (e < E_L + E_P) atomicAdd(&count[N_L + tgtP[e - E_L]], 1);
    else if (e < E_L + E_P + E_X) atomicAdd(&count[N_L + N_P + ctgt[e - E_L - E_P]], 1);
}

// ---- hierarchical scan ----
__global__ __launch_bounds__(256) void scan_blocksum_kernel(const int* __restrict__ count,
                                                            int* __restrict__ bsum, int n) {
    int b = blockIdx.x, t = threadIdx.x;
    int base = b * 4096 + t * 16;
    int s = 0;
#pragma unroll
    for (int k = 0; k < 16; ++k) {
        int idx = base + k;
        s += (idx < n) ? count[idx] : 0;
    }
#pragma unroll
    for (int off = 1; off < 64; off <<= 1) s += __shfl_xor(s, off, 64);
    __shared__ int ws[4];
    int lane = t & 63, wid = t >> 6;
    if (lane == 0) ws[wid] = s;
    __syncthreads();
    if (t == 0) bsum[b] = ws[0] + ws[1] + ws[2] + ws[3];
}

__global__ void scan_top_kernel(int* __restrict__ bsum, int nb, float* __restrict__ csc) {
    if (threadIdx.x == 0) {
        int run = 0;
        for (int i = 0; i < nb; ++i) { int c = bsum[i]; bsum[i] = run; run += c; }
        csc[0] = -3.4e38f; csc[1] = 0.f;
    }
}

__global__ __launch_bounds__(256) void scan_apply_kernel(const int* __restrict__ count,
        const int* __restrict__ bsum, int* __restrict__ rowptr, int* __restrict__ cursor,
        int n, int E) {
    int b = blockIdx.x, t = threadIdx.x;
    int base = b * 4096 + t * 16;
    int v[16];
    int s = 0;
#pragma unroll
    for (int k = 0; k < 16; ++k) {
        int idx = base + k;
        v[k] = (idx < n) ? count[idx] : 0;
        s += v[k];
    }
    int lane = t & 63, wid = t >> 6;
    int inc = s;
#pragma unroll
    for (int off = 1; off < 64; off <<= 1) {
        int o = __shfl_up(inc, off, 64);
        if (lane >= off) inc += o;
    }
    __shared__ int ws[4];
    if (lane == 63) ws[wid] = inc;
    __syncthreads();
    int woff = 0;
    for (int w = 0; w < wid; ++w) woff += ws[w];
    int prefix = bsum[b] + woff + (inc - s);
#pragma unroll
    for (int k = 0; k < 16; ++k) {
        int idx = base + k;
        if (idx < n) { rowptr[idx] = prefix; cursor[idx] = prefix; prefix += v[k]; }
    }
    if (b == 0 && t == 0) rowptr[n] = E;
}

// combined CSR fill, 4-byte packed payloads
__global__ __launch_bounds__(256) void pre_all_kernel(const int* __restrict__ eL,
        const int* __restrict__ eP, const int* __restrict__ csrc, const int* __restrict__ ctgt,
        const float* __restrict__ posL, const float* __restrict__ posP,
        int* __restrict__ cursor, unsigned int* __restrict__ sdp,
        int E_L, int E_P, int E_X, int N_L, int N_P) {
    int e = blockIdx.x * blockDim.x + threadIdx.x;
    if (e >= E_L + E_P + E_X) return;
    unsigned int pack;
    int node;
    if (e < E_L + E_P) {
        const int* ed; const float* pos; int idx, E, nbase;
        if (e < E_L) { ed = eL; pos = posL; idx = e; E = E_L; nbase = 0; }
        else         { ed = eP; pos = posP; idx = e - E_L; E = E_P; nbase = N_L; }
        int si = ed[idx], ti = ed[E + idx];
        node = nbase + ti;
        float dx = pos[si * 3 + 0] - pos[ti * 3 + 0];
        float dy = pos[si * 3 + 1] - pos[ti * 3 + 1];
        float dz = pos[si * 3 + 2] - pos[ti * 3 + 2];
        float dist = sqrtf(dx * dx + dy * dy + dz * dz);
        int dq = min((int)(dist * 4096.f), 65535);
        pack = (unsigned int)(si + nbase) | ((unsigned int)dq << 16);
    } else {
        int idx = e - E_L - E_P;
        int ti = ctgt[idx];
        pack = (unsigned int)csrc[idx] | ((unsigned int)ti << 16);
        node = N_L + N_P + ti;
    }
    int p = atomicAdd(&cursor[node], 1);
    sdp[p] = pack;
}

// packed RBF@We table
__global__ __launch_bounds__(96) void rbf_table_pack_kernel(const float* __restrict__ We_L,
        const float* __restrict__ We_P, unsigned int* __restrict__ T2_L,
        unsigned int* __restrict__ T2_P) {
    int b = blockIdx.x;
    const float* We = (b < 1024) ? We_L : We_P;
    unsigned int* T2 = (b < 1024) ? T2_L : T2_P;
    int i = (b < 1024) ? b : b - 1024;
    int h = threadIdx.x;
    float d0 = (float)i * 0.015625f, d1 = (float)(i + 1) * 0.015625f;
    float a0 = 0.f, a1 = 0.f;
#pragma unroll
    for (int g = 0; g < 16; ++g) {
        float w = We[g * 96 + h];
        float t0 = d0 - 0.66666667f * (float)g;
        float t1 = d1 - 0.66666667f * (float)g;
        a0 += __expf(-1.125f * t0 * t0) * w;
        a1 += __expf(-1.125f * t1 * t1) * w;
    }
    T2[i * 96 + h] = (unsigned int)f2bf(a0) | ((unsigned int)f2bf(a1 - a0) << 16);
}

// Combined L+P GATv2: half-wave per combined node; xr bf16.
__global__ __launch_bounds__(256) void gat_all_kernel(const int* __restrict__ rowptr,
        const unsigned int* __restrict__ sdp, const unsigned short* __restrict__ xlb,
        const unsigned short* __restrict__ xrb,
        const unsigned int* __restrict__ T2_L, const unsigned int* __restrict__ T2_P,
        const float* __restrict__ att_L, const float* __restrict__ att_P,
        const float* __restrict__ bias_L, const float* __restrict__ bias_P,
        float* __restrict__ s_L, float* __restrict__ s_P, int N_L, int Ncomb) {
    int tid = threadIdx.x;
    int l = tid & 31;
    int n = blockIdx.x * 8 + (tid >> 5);
    if (n >= Ncomb) return;
    bool isL = n < N_L;
    const unsigned int* T2 = isL ? T2_L : T2_P;
    const float* att = isL ? att_L : att_P;
    const float* bias = isL ? bias_L : bias_P;
    float* srow = isL ? (s_L + (size_t)n * 96) : (s_P + (size_t)(n - N_L) * 96);
    float att0 = att[l], att1 = att[32 + l], att2 = att[64 + l];
    size_t nb = (size_t)n * 96;
    float xr0 = bf2f(xrb[nb + l]), xr1 = bf2f(xrb[nb + 32 + l]), xr2 = bf2f(xrb[nb + 64 + l]);
    int beg = rowptr[n], end = rowptr[n + 1];
    float m = -3.4e38f, d = 0.f, a0 = 0.f, a1 = 0.f, a2 = 0.f;
    for (int j = beg; j < end; j += 4) {
        unsigned int tp0[4], tp1[4], tp2[4];
        unsigned short xs0[4], xs1[4], xs2[4];
        float ff[4];
#pragma unroll
        for (int k = 0; k < 4; ++k) {
            int jj = min(j + k, end - 1);
            unsigned int u = sdp[jj];
            int src = (int)(u & 0xffffu);
            int dq = (int)(u >> 16);
            int i = dq >> 6;
            ff[k] = (float)(dq & 63) * 0.015625f;
            const unsigned int* tr = T2 + (size_t)i * 96;
            tp0[k] = tr[l]; tp1[k] = tr[32 + l]; tp2[k] = tr[64 + l];
            const unsigned short* xp = xlb + (size_t)src * 96;
            xs0[k] = xp[l]; xs1[k] = xp[32 + l]; xs2[k] = xp[64 + l];
        }
        float y0[4], y1[4], y2[4], lt[4];
#pragma unroll
        for (int k = 0; k < 4; ++k) {
            y0[k] = bf2f(xs0[k]); y1[k] = bf2f(xs1[k]); y2[k] = bf2f(xs2[k]);
            float v0 = y0[k] + xr0 + bf_lo(tp0[k]) + ff[k] * bf_hi(tp0[k]);
            float v1 = y1[k] + xr1 + bf_lo(tp1[k]) + ff[k] * bf_hi(tp1[k]);
            float v2 = y2[k] + xr2 + bf_lo(tp2[k]) + ff[k] * bf_hi(tp2[k]);
            v0 = fmaxf(v0, 0.f) + 0.2f * fminf(v0, 0.f);
            v1 = fmaxf(v1, 0.f) + 0.2f * fminf(v1, 0.f);
            v2 = fmaxf(v2, 0.f) + 0.2f * fminf(v2, 0.f);
            float t = v0 * att0 + v1 * att1 + v2 * att2;
#pragma unroll
            for (int off = 1; off < 32; off <<= 1) t += __shfl_xor(t, off, 64);
            lt[k] = (j + k < end) ? t : -3.4e38f;
        }
        float bm = fmaxf(fmaxf(lt[0], lt[1]), fmaxf(lt[2], lt[3]));
        float nm = fmaxf(m, bm);
        float sc = __expf(m - nm);
        d *= sc; a0 *= sc; a1 *= sc; a2 *= sc;
#pragma unroll
        for (int k = 0; k < 4; ++k) {
            float w = __expf(lt[k] - nm);
            d += w;
            a0 += w * y0[k]; a1 += w * y1[k]; a2 += w * y2[k];
        }
        m = nm;
    }
    float agg0 = (d > 0.f) ? a0 / d : 0.f;
    float agg1 = (d > 0.f) ? a1 / d : 0.f;
    float agg2 = (d > 0.f) ? a2 / d : 0.f;
    srow[l]      += silu_f(agg0 + bias[l]);
    srow[32 + l] += silu_f(agg1 + bias[32 + l]);
    srow[64 + l] += silu_f(agg2 + bias[64 + l]);
}

// edge-parallel cross logits
__global__ __launch_bounds__(256) void cross_logit_e_kernel(const unsigned int* __restrict__ sdX,
        const unsigned short* __restrict__ qnb, const unsigned short* __restrict__ knb,
        float* __restrict__ clog_s, float* __restrict__ csc, int E) {
    int e = blockIdx.x * blockDim.x + threadIdx.x;
    float logit = -3.4e38f;
    if (e < E) {
        unsigned int u = sdX[e];
        int src = (int)(u & 0xffffu);
        int tgt = (int)(u >> 16);
        const uint4* q4 = (const uint4*)(qnb + (size_t)tgt * 96);
        const uint4* k4 = (const uint4*)(knb + (size_t)src * 96);
        float acc = 0.f;
#pragma unroll
        for (int i = 0; i < 12; ++i) {
            uint4 qa = q4[i], ka = k4[i];
            acc += bfdot(qa.x, ka.x) + bfdot(qa.y, ka.y) + bfdot(qa.z, ka.z) + bfdot(qa.w, ka.w);
        }
        logit = acc * 0.125f;
        clog_s[e] = logit;
    }
    __shared__ float red[256];
    red[threadIdx.x] = logit; __syncthreads();
    for (int s = 128; s > 0; s >>= 1) {
        if (threadIdx.x < s) red[threadIdx.x] = fmaxf(red[threadIdx.x], red[threadIdx.x + s]);
        __syncthreads();
    }
    if (threadIdx.x == 0) atomicMaxF(&csc[0], red[0]);
}

__global__ __launch_bounds__(256) void cross_denom_kernel(const float* __restrict__ clog_s,
                                                          float* __restrict__ csc, int E) {
    int e = blockIdx.x * blockDim.x + threadIdx.x;
    float a = 0.f;
    float mg = csc[0];
    if (e < E) a = __expf(clog_s[e] - mg);
    __shared__ float red[256];
    red[threadIdx.x] = a; __syncthreads();
    for (int s = 128; s > 0; s >>= 1) {
        if (threadIdx.x < s) red[threadIdx.x] += red[threadIdx.x + s];
        __syncthreads();
    }
    if (threadIdx.x == 0) atomicAdd(&csc[1], red[0]);
}

// cross apply: half-wave per L node
__global__ __launch_bounds__(256) void cross_apply_v4_kernel(const int* __restrict__ rowptr,
        const unsigned int* __restrict__ sdp, const float* __restrict__ clog_s,
        const unsigned short* __restrict__ vnb, const float* __restrict__ csc,
        float* __restrict__ sL, int N, int baseX) {
    int tid = threadIdx.x;
    int l = tid & 31;
    int n = blockIdx.x * 8 + (tid >> 5);
    if (n >= N) return;
    int beg = rowptr[n], end = rowptr[n + 1];
    if (beg == end) return;
    float M = csc[0], invD = 1.f / csc[1];
    float a0 = 0.f, a1 = 0.f, a2 = 0.f;
    for (int j = beg; j < end; j += 4) {
        unsigned short v0[4], v1[4], v2[4]; float w[4];
#pragma unroll
        for (int k = 0; k < 4; ++k) {
            int jj = min(j + k, end - 1);
            int src = (int)(sdp[jj] & 0xffffu);
            const unsigned short* vp = vnb + (size_t)src * 96;
            v0[k] = vp[l]; v1[k] = vp[32 + l]; v2[k] = vp[64 + l];
            w[k] = (j + k < end) ? __expf(clog_s[jj - baseX] - M) : 0.f;
        }
#pragma unroll
        for (int k = 0; k < 4; ++k) {
            a0 += w[k] * bf2f(v0[k]); a1 += w[k] * bf2f(v1[k]); a2 += w[k] * bf2f(v2[k]);
        }
    }
    size_t nb = (size_t)n * 96;
    sL[nb + l]      += a0 * invD;
    sL[nb + 32 + l] += a1 * invD;
    sL[nb + 64 + l] += a2 * invD;
}

// ---------- vectorized dense kernels ----------

// fused embed + dual GAT-linear; 32 rows/block, bf16 staging for stage 2.
// LDS = 32*167*4 + 32*96*2 = 27.5 KB -> 5 blocks/CU -> 1280-block grid fully co-resident.
__global__ __launch_bounds__(192) void enc_all_kernel(
        const float* __restrict__ x_L, const float* __restrict__ x_P,
        const float* __restrict__ WembL, const float* __restrict__ bembL,
        const float* __restrict__ WembP, const float* __restrict__ bembP,
        const float* __restrict__ WlL, const float* __restrict__ blL,
        const float* __restrict__ WrL, const float* __restrict__ brL,
        const float* __restrict__ WlP, const float* __restrict__ blP,
        const float* __restrict__ WrP, const float* __restrict__ brP,
        float* __restrict__ s_L, float* __restrict__ s_P,
        unsigned short* __restrict__ xlb, unsigned short* __restrict__ xrb,
        int N_L, int N_P, int D_L, int D_P, int BL) {
    __shared__ float xs[32 * 167];
    __shared__ unsigned short ssb[32 * 96];
    int b = blockIdx.x;
    bool isL = b < BL;
    const float* x    = isL ? x_L : x_P;
    const float* Wemb = isL ? WembL : WembP;
    const float* bemb = isL ? bembL : bembP;
    const float* Wl   = isL ? WlL : WlP;
    const float* bl   = isL ? blL : blP;
    const float* Wr   = isL ? WrL : WrP;
    const float* br   = isL ? brL : brP;
    float* sOut = isL ? s_L : s_P;
    int N = isL ? N_L : N_P;
    int D = isL ? D_L : D_P;
    int n0 = (isL ? b : b - BL) * 32;
    int cbase = isL ? 0 : N_L;
    int t = threadIdx.x;
    int hg = t % 24, h4 = hg * 4;
    int rg = t / 24;  // 0..7, rows rg*4..rg*4+3
    for (int i = t; i < 32 * D; i += 192) {
        int r = i / D, dd = i - r * D, nn = n0 + r;
        xs[i] = (nn < N) ? x[(size_t)nn * D + dd] : 0.f;
    }
    __syncthreads();
    float4 be = *(const float4*)&bemb[h4];
    float acc[4][4];
#pragma unroll
    for (int r = 0; r < 4; ++r) { acc[r][0] = be.x; acc[r][1] = be.y; acc[r][2] = be.z; acc[r][3] = be.w; }
    const float* xrow = &xs[rg * 4 * D];
    for (int dd = 0; dd < D; ++dd) {
        float4 w = *(const float4*)&Wemb[dd * 96 + h4];
#pragma unroll
        for (int r = 0; r < 4; ++r) {
            float xv = xrow[r * D + dd];
            acc[r][0] += xv * w.x; acc[r][1] += xv * w.y;
            acc[r][2] += xv * w.z; acc[r][3] += xv * w.w;
        }
    }
#pragma unroll
    for (int r = 0; r < 4; ++r) {
        int row = rg * 4 + r, nn = n0 + row;
        float4 v = make_float4(silu_f(acc[r][0]), silu_f(acc[r][1]),
                               silu_f(acc[r][2]), silu_f(acc[r][3]));
        *(ushort4*)&ssb[row * 96 + h4] = make_ushort4(f2bf(v.x), f2bf(v.y), f2bf(v.z), f2bf(v.w));
        if (nn < N) *(float4*)&sOut[(size_t)nn * 96 + h4] = v;
    }
    __syncthreads();
    float4 b1v = *(const float4*)&bl[h4];
    float4 b2v = *(const float4*)&br[h4];
    float a1[4][4], a2[4][4];
#pragma unroll
    for (int r = 0; r < 4; ++r) {
        a1[r][0] = b1v.x; a1[r][1] = b1v.y; a1[r][2] = b1v.z; a1[r][3] = b1v.w;
        a2[r][0] = b2v.x; a2[r][1] = b2v.y; a2[r][2] = b2v.z; a2[r][3] = b2v.w;
    }
    const unsigned short* srow = &ssb[rg * 4 * 96];
    for (int k = 0; k < 96; ++k) {
        float4 w1 = *(const float4*)&Wl[k * 96 + h4];
        float4 w2 = *(const float4*)&Wr[k * 96 + h4];
#pragma unroll
        for (int r = 0; r < 4; ++r) {
            float xv = bf2f(srow[r * 96 + k]);
            a1[r][0] += xv * w1.x; a1[r][1] += xv * w1.y; a1[r][2] += xv * w1.z; a1[r][3] += xv * w1.w;
            a2[r][0] += xv * w2.x; a2[r][1] += xv * w2.y; a2[r][2] += xv * w2.z; a2[r][3] += xv * w2.w;
        }
    }
#pragma unroll
    for (int r = 0; r < 4; ++r) {
        int nn = n0 + rg * 4 + r;
        if (nn < N) {
            size_t o = (size_t)(cbase + nn) * 96 + h4;
            *(ushort4*)&xlb[o] = make_ushort4(f2bf(a1[r][0]), f2bf(a1[r][1]), f2bf(a1[r][2]), f2bf(a1[r][3]));
            *(ushort4*)&xrb[o] = make_ushort4(f2bf(a2[r][0]), f2bf(a2[r][1]), f2bf(a2[r][2]), f2bf(a2[r][3]));
        }
    }
}

// q (L) / k,v (P) projections; 32 rows/block, 4h x 4 rows per thread.
__global__ __launch_bounds__(192) void qkv_all_kernel(
        const float* __restrict__ s_L, const float* __restrict__ s_P,
        const float* __restrict__ Wq, const float* __restrict__ bq,
        const float* __restrict__ Wk, const float* __restrict__ bk,
        const float* __restrict__ Wv, const float* __restrict__ bv,
        unsigned short* __restrict__ qnb, unsigned short* __restrict__ knb,
        unsigned short* __restrict__ vnb, int N_L, int N_P, int BL) {
    __shared__ float xs[32 * 96];
    int b = blockIdx.x;
    bool isL = b < BL;
    const float* s = isL ? s_L : s_P;
    int N = isL ? N_L : N_P;
    int n0 = (isL ? b : b - BL) * 32;
    int t = threadIdx.x;
    int hg = t % 24, h4 = hg * 4;
    int rg = t / 24;
    for (int i = t; i < 32 * 96; i += 192) {
        int r = i / 96, c = i - r * 96, nn = n0 + r;
        xs[i] = (nn < N) ? s[(size_t)nn * 96 + c] : 0.f;
    }
    __syncthreads();
    const float* srow = &xs[rg * 4 * 96];
    if (isL) {
        float4 bb = *(const float4*)&bq[h4];
        float a1[4][4];
#pragma unroll
        for (int r = 0; r < 4; ++r) { a1[r][0] = bb.x; a1[r][1] = bb.y; a1[r][2] = bb.z; a1[r][3] = bb.w; }
        for (int k = 0; k < 96; ++k) {
            float4 w = *(const float4*)&Wq[k * 96 + h4];
#pragma unroll
            for (int r = 0; r < 4; ++r) {
                float xv = srow[r * 96 + k];
                a1[r][0] += xv * w.x; a1[r][1] += xv * w.y; a1[r][2] += xv * w.z; a1[r][3] += xv * w.w;
            }
        }
#pragma unroll
        for (int r = 0; r < 4; ++r) {
            int nn = n0 + rg * 4 + r;
            if (nn < N)
                *(ushort4*)&qnb[(size_t)nn * 96 + h4] =
                    make_ushort4(f2bf(a1[r][0]), f2bf(a1[r][1]), f2bf(a1[r][2]), f2bf(a1[r][3]));
        }
    } else {
        float4 bb1 = *(const float4*)&bk[h4];
        float4 bb2 = *(const float4*)&bv[h4];
        float a1[4][4], a2[4][4];
#pragma unroll
        for (int r = 0; r < 4; ++r) {
            a1[r][0] = bb1.x; a1[r][1] = bb1.y; a1[r][2] = bb1.z; a1[r][3] = bb1.w;
            a2[r][0] = bb2.x; a2[r][1] = bb2.y; a2[r][2] = bb2.z; a2[r][3] = bb2.w;
        }
        for (int k = 0; k < 96; ++k) {
            float4 w1 = *(const float4*)&Wk[k * 96 + h4];
            float4 w2 = *(const float4*)&Wv[k * 96 + h4];
#pragma unroll
            for (int r = 0; r < 4; ++r) {
                float xv = srow[r * 96 + k];
                a1[r][0] += xv * w1.x; a1[r][1] += xv * w1.y; a1[r][2] += xv * w1.z; a1[r][3] += xv * w1.w;
                a2[r][0] += xv * w2.x; a2[r][1] += xv * w2.y; a2[r][2] += xv * w2.z; a2[r][3] += xv * w2.w;
            }
        }
#pragma unroll
        for (int r = 0; r < 4; ++r) {
            int nn = n0 + rg * 4 + r;
            if (nn < N) {
                *(ushort4*)&knb[(size_t)nn * 96 + h4] =
                    make_ushort4(f2bf(a1[r][0]), f2bf(a1[r][1]), f2bf(a1[r][2]), f2bf(a1[r][3]));
                *(ushort4*)&vnb[(size_t)nn * 96 + h4] =
                    make_ushort4(f2bf(a2[r][0]), f2bf(a2[r][1]), f2bf(a2[r][2]), f2bf(a2[r][3]));
            }
        }
    }
}

// SSM: 8 rows/block.
__global__ __launch_bounds__(192) void ssm3_kernel(float* __restrict__ sL,
        const float* __restrict__ Win, const float* __restrict__ b_in,
        const float* __restrict__ Wout, const float* __restrict__ bout, int N) {
    __shared__ float row[8 * 96];
    __shared__ float u[8 * 192];
    int t = threadIdx.x;
    int n0 = blockIdx.x * 8;
    for (int i = t; i < 8 * 96; i += 192) {
        int r = i / 96, c = i - r * 96, nn = n0 + r;
        row[i] = (nn < N) ? sL[(size_t)nn * 96 + c] : 0.f;
    }
    __syncthreads();
    {
        int cg = t % 48, c4 = cg * 4;
        int rg = t / 48;
        float4 bb = *(const float4*)&b_in[c4];
        float a[2][4];
#pragma unroll
        for (int r = 0; r < 2; ++r) { a[r][0] = bb.x; a[r][1] = bb.y; a[r][2] = bb.z; a[r][3] = bb.w; }
        const float* rr = &row[rg * 2 * 96];
        for (int k = 0; k < 96; ++k) {
            float4 w = *(const float4*)&Win[k * 384 + c4];
#pragma unroll
            for (int r = 0; r < 2; ++r) {
                float xv = rr[r * 96 + k];
                a[r][0] += xv * w.x; a[r][1] += xv * w.y; a[r][2] += xv * w.z; a[r][3] += xv * w.w;
            }
        }
#pragma unroll
        for (int r = 0; r < 2; ++r) {
            int ro = rg * 2 + r;
            u[ro * 192 + c4 + 0] = silu_f(a[r][0]);
            u[ro * 192 + c4 + 1] = silu_f(a[r][1]);
            u[ro * 192 + c4 + 2] = silu_f(a[r][2]);
            u[ro * 192 + c4 + 3] = silu_f(a[r][3]);
        }
    }
    __syncthreads();
    {
        int hg = t % 24, h4 = hg * 4;
        int rg2 = t / 24;
        float4 bb = *(const float4*)&bout[h4];
        float a[4] = {bb.x, bb.y, bb.z, bb.w};
        const float* ur = &u[rg2 * 192];
        for (int j = 0; j < 192; ++j) {
            float4 w = *(const float4*)&Wout[j * 96 + h4];
            float uv = ur[j];
            a[0] += uv * w.x; a[1] += uv * w.y; a[2] += uv * w.z; a[3] += uv * w.w;
        }
        int nn = n0 + rg2;
        if (nn < N) {
            float4 rv = *(const float4*)&row[rg2 * 96 + h4];
            *(float4*)&sL[(size_t)nn * 96 + h4] =
                make_float4(rv.x + a[0], rv.y + a[1], rv.z + a[2], rv.w + a[3]);
        }
    }
}

// head: 32 rows/block.
__global__ __launch_bounds__(192) void head3_kernel(const float* __restrict__ sL,
        const float* __restrict__ W1, const float* __restrict__ b1,
        const float* __restrict__ W2, const float* __restrict__ b2,
        float* __restrict__ out, int N) {
    __shared__ float buf[32 * 96];
    __shared__ float tt[32 * 96];
    int t = threadIdx.x;
    int n0 = blockIdx.x * 32;
    for (int i = t; i < 32 * 96; i += 192) {
        int r = i / 96, c = i - r * 96, nn = n0 + r;
        buf[i] = (nn < N) ? sL[(size_t)nn * 96 + c] : 0.f;
    }
    __syncthreads();
    int hg = t % 24, h4 = hg * 4;
    int rg = t / 24;
    float4 bb = *(const float4*)&b1[h4];
    float a[4][4];
#pragma unroll
    for (int r = 0; r < 4; ++r) { a[r][0] = bb.x; a[r][1] = bb.y; a[r][2] = bb.z; a[r][3] = bb.w; }
    const float* srow = &buf[rg * 4 * 96];
    for (int k = 0; k < 96; ++k) {
        float4 w = *(const float4*)&W1[k * 96 + h4];
#pragma unroll
        for (int r = 0; r < 4; ++r) {
            float xv = srow[r * 96 + k];
            a[r][0] += xv * w.x; a[r][1] += xv * w.y; a[r][2] += xv * w.z; a[r][3] += xv * w.w;
        }
    }
#pragma unroll
    for (int r = 0; r < 4; ++r) {
        int row = rg * 4 + r;
        *(float4*)&tt[row * 96 + h4] = make_float4(silu_f(a[r][0]), silu_f(a[r][1]),
                                                   silu_f(a[r][2]), silu_f(a[r][3]));
    }
    __syncthreads();
    if (t < 96) {
        int r = t / 3, c = t - r * 3;
        float o = b2[c];
        const float* tr = &tt[r * 96];
        for (int j = 0; j < 96; ++j) o += tr[j] * W2[j * 3 + c];
        int nn = n0 + r;
        if (nn < N) out[nn * 3 + c] = o;
    }
}

static inline int cdiv(int a, int b) { return (a + b - 1) / b; }

extern "C" void kernel_launch(void* const* d_in, const int* in_sizes, int n_in,
                              void* d_out, int out_size, void* d_ws, size_t ws_size,
                              hipStream_t stream) {
    const float* x_L   = (const float*)d_in[0];
    const float* pos_L = (const float*)d_in[1];
    const float* x_P   = (const float*)d_in[2];
    const float* pos_P = (const float*)d_in[3];
    const int* edge_L = (const int*)d_in[4];
    const int* edge_P = (const int*)d_in[5];
    const int* csrc   = (const int*)d_in[6];
    const int* ctgt   = (const int*)d_in[7];
    const float *Wemb_L = (const float*)d_in[8],  *bemb_L = (const float*)d_in[9];
    const float *Wl_L = (const float*)d_in[10], *bl_L = (const float*)d_in[11];
    const float *Wr_L = (const float*)d_in[12], *br_L = (const float*)d_in[13];
    const float *We_L = (const float*)d_in[14], *att_L = (const float*)d_in[15], *bias_L = (const float*)d_in[16];
    const float *Wemb_P = (const float*)d_in[17], *bemb_P = (const float*)d_in[18];
    const float *Wl_P = (const float*)d_in[19], *bl_P = (const float*)d_in[20];
    const float *Wr_P = (const float*)d_in[21], *br_P = (const float*)d_in[22];
    const float *We_P = (const float*)d_in[23], *att_P = (const float*)d_in[24], *bias_P = (const float*)d_in[25];
    const float *Win = (const float*)d_in[26], *b_in = (const float*)d_in[27];
    const float *Wout = (const float*)d_in[28], *bout = (const float*)d_in[29];
    const float *Wq = (const float*)d_in[30], *bq = (const float*)d_in[31];
    const float *Wk = (const float*)d_in[32], *bk = (const float*)d_in[33];
    const float *Wv = (const float*)d_in[34], *bv = (const float*)d_in[35];
    const float *W1 = (const float*)d_in[36], *b1 = (const float*)d_in[37];
    const float *W2 = (const float*)d_in[38], *b2 = (const float*)d_in[39];

    const int N_L = in_sizes[1] / 3;
    const int N_P = in_sizes[3] / 3;
    const int E_L = in_sizes[4] / 2;
    const int E_P = in_sizes[5] / 2;
    const int E_X = in_sizes[6];
    const int D_L = in_sizes[0] / N_L;
    const int D_P = in_sizes[2] / N_P;
    const int Ncomb = N_L + N_P;
    const int Ntot = N_L + N_P + N_L;
    const int Etot = E_L + E_P + E_X;
    const int baseX = E_L + E_P;

    // workspace layout
    float* ws = (float*)d_ws;
    float*          s_L    = ws;                                     // N_L*96 f32
    float*          s_P    = s_L + (size_t)N_L * 96;                 // N_P*96 f32
    unsigned short* xrb    = (unsigned short*)(s_P + (size_t)N_P * 96);  // Ncomb*96 bf16
    unsigned short* xlb    = xrb + (size_t)Ncomb * 96;               // Ncomb*96 bf16
    unsigned short* knb    = xlb + (size_t)Ncomb * 96;               // N_P*96 bf16
    unsigned short* vnb    = knb + (size_t)N_P * 96;                 // N_P*96 bf16
    unsigned short* qnb    = vnb + (size_t)N_P * 96;                 // N_L*96 bf16
    unsigned int*   sdp    = (unsigned int*)(qnb + (size_t)N_L * 96);// Etot u32
    float*          clog_s = (float*)(sdp + (size_t)Etot);           // E_X f32
    unsigned int*   T2_L   = (unsigned int*)(clog_s + (size_t)E_X);  // 1024*96
    unsigned int*   T2_P   = T2_L + 1024 * 96;                       // 1024*96
    int*            rowptr = (int*)(T2_P + 1024 * 96);               // Ntot+1
    int*            count  = rowptr + (size_t)Ntot + 1;              // Ntot
    int*            cursor = count + (size_t)Ntot;                   // Ntot
    float*          csc    = (float*)(cursor + (size_t)Ntot);        // 2
    int*            bsum   = (int*)(csc + 2);                        // <=16

    const int BL32 = cdiv(N_L, 32), BP32 = cdiv(N_P, 32);

    // tables + combined CSR build
    rbf_table_pack_kernel<<<2048, 96, 0, stream>>>(We_L, We_P, T2_L, T2_P);
    fill_i<<<cdiv(Ntot, 256), 256, 0, stream>>>(count, 0, Ntot);
    hist_all_kernel<<<cdiv(Etot, 256), 256, 0, stream>>>(edge_L + E_L, edge_P + E_P, ctgt,
        count, E_L, E_P, E_X, N_L, N_P);
    scan_blocksum_kernel<<<cdiv(Ntot, 4096), 256, 0, stream>>>(count, bsum, Ntot);
    scan_top_kernel<<<1, 64, 0, stream>>>(bsum, cdiv(Ntot, 4096), csc);
    scan_apply_kernel<<<cdiv(Ntot, 4096), 256, 0, stream>>>(count, bsum, rowptr, cursor, Ntot, Etot);
    pre_all_kernel<<<cdiv(Etot, 256), 256, 0, stream>>>(edge_L, edge_P, csrc, ctgt,
        pos_L, pos_P, cursor, sdp, E_L, E_P, E_X, N_L, N_P);

    // fused embed + gat-linears for both graphs (32 rows/block, bf16 staging)
    enc_all_kernel<<<BL32 + BP32, 192, 0, stream>>>(x_L, x_P, Wemb_L, bemb_L, Wemb_P, bemb_P,
        Wl_L, bl_L, Wr_L, br_L, Wl_P, bl_P, Wr_P, br_P,
        s_L, s_P, xlb, xrb, N_L, N_P, D_L, D_P, BL32);

    // combined L+P GAT
    gat_all_kernel<<<cdiv(Ncomb, 8), 256, 0, stream>>>(rowptr, sdp, xlb, xrb, T2_L, T2_P,
        att_L, att_P, bias_L, bias_P, s_L, s_P, N_L, Ncomb);

    // SSM (L)
    ssm3_kernel<<<cdiv(N_L, 8), 192, 0, stream>>>(s_L, Win, b_in, Wout, bout, N_L);

    // cross attention
    qkv_all_kernel<<<BL32 + BP32, 192, 0, stream>>>(s_L, s_P, Wq, bq, Wk, bk, Wv, bv,
        qnb, knb, vnb, N_L, N_P, BL32);
    cross_logit_e_kernel<<<cdiv(E_X, 256), 256, 0, stream>>>(sdp + (size_t)baseX, qnb, knb,
        clog_s, csc, E_X);
    cross_denom_kernel<<<cdiv(E_X, 256), 256, 0, stream>>>(clog_s, csc, E_X);
    cross_apply_v4_kernel<<<cdiv(N_L, 8), 256, 0, stream>>>(rowptr + N_L + N_P, sdp,
        clog_s, vnb, csc, s_L, N_L, baseX);

    // head
    head3_kernel<<<cdiv(N_L, 32), 192, 0, stream>>>(s_L, W1, b1, W2, b2, (float*)d_out, N_L);
}